// Round 1
// baseline (5374.636 us; speedup 1.0000x reference)
//
#include <hip/hip_runtime.h>

// LinearRNN: ys[t] = A^(t+1) @ y_init[0], t = 0..8191, D = 2048.
// Strategy: row-vector convention with T = A^T so each step is row·T (NN GEMM).
//   1) transpose A -> T (ws)
//   2) log-doubling: rows[m..2m) = rows[0..m) · T^m ; square T^m -> T^2m  (8x)
//   3) chain: rows[256j..) = rows[256(j-1)..) · T^256  (31 sequential GEMMs, M=256)
// All fp32 vector ALU (no fp32 MFMA on CDNA4). 49 kernel launches total.

#define D 2048
#define STEPS 8192
#define KB 256  // chain block: 8 squarings, 31 chain GEMMs of M=256

// ---------------- transpose: T[p][q] = A[q][p] ----------------
__global__ void transpose_k(const float* __restrict__ A, float* __restrict__ T) {
    __shared__ float tile[32][33];
    const int bx = blockIdx.x * 32, by = blockIdx.y * 32;
    const int tx = threadIdx.x, ty = threadIdx.y;  // (32, 8)
#pragma unroll
    for (int i = 0; i < 32; i += 8)
        tile[ty + i][tx] = A[(size_t)(by + ty + i) * D + bx + tx];
    __syncthreads();
#pragma unroll
    for (int i = 0; i < 32; i += 8)
        T[(size_t)(bx + ty + i) * D + by + tx] = tile[tx][ty + i];
}

// ---------------- row-block GEMM: C[M][D] = X[M][D] * W[D][D] ----------------
// Tile 32(rows) x 64(cols), BK=16, 256 threads, 2x4 micro-tile per thread.
// Used for the seed (M=1), doubling rows (M=1..128) and chain steps (M=256).
__global__ __launch_bounds__(256) void gemm_rows(const float* __restrict__ X,
                                                 const float* __restrict__ W,
                                                 float* __restrict__ C, int M) {
    __shared__ float As[16][34];  // [k][m], +2 pad (float2-aligned)
    __shared__ float Bs[16][68];  // [k][n], +4 pad (float4-aligned)
    const int n0 = blockIdx.x * 64;
    const int m0 = blockIdx.y * 32;
    const int tid = threadIdx.x;
    const int ty = tid >> 4, tx = tid & 15;
    // staging indices
    const int rs = tid >> 3;            // 0..31 (A row within tile)
    const int ks = (tid & 7) * 2;       // 0,2,..,14
    const int rclamp = min(m0 + rs, M - 1);
    const int kb = tid >> 4;            // 0..15 (W row within tile)
    const int nb = (tid & 15) * 4;

    float acc[2][4] = {{0.f, 0.f, 0.f, 0.f}, {0.f, 0.f, 0.f, 0.f}};

    for (int k0 = 0; k0 < D; k0 += 16) {
        float2 xa = *reinterpret_cast<const float2*>(&X[(size_t)rclamp * D + k0 + ks]);
        float4 wb = *reinterpret_cast<const float4*>(&W[(size_t)(k0 + kb) * D + n0 + nb]);
        As[ks][rs] = xa.x;
        As[ks + 1][rs] = xa.y;
        *reinterpret_cast<float4*>(&Bs[kb][nb]) = wb;
        __syncthreads();
#pragma unroll
        for (int kk = 0; kk < 16; ++kk) {
            float2 a = *reinterpret_cast<const float2*>(&As[kk][ty * 2]);
            float4 b = *reinterpret_cast<const float4*>(&Bs[kk][tx * 4]);
            acc[0][0] += a.x * b.x; acc[0][1] += a.x * b.y;
            acc[0][2] += a.x * b.z; acc[0][3] += a.x * b.w;
            acc[1][0] += a.y * b.x; acc[1][1] += a.y * b.y;
            acc[1][2] += a.y * b.z; acc[1][3] += a.y * b.w;
        }
        __syncthreads();
    }
#pragma unroll
    for (int i = 0; i < 2; ++i) {
        const int m = m0 + ty * 2 + i;
        if (m < M) {
            float4 v = make_float4(acc[i][0], acc[i][1], acc[i][2], acc[i][3]);
            *reinterpret_cast<float4*>(&C[(size_t)m * D + n0 + tx * 4]) = v;
        }
    }
}

// ---------------- big GEMM (matrix squaring): C[D][D] = X * W ----------------
// Tile 128x64, BK=16, 256 threads, 8x4 micro-tile. Grid 32x16 = 512 WGs (2/CU).
__global__ __launch_bounds__(256, 2) void gemm_big(const float* __restrict__ X,
                                                   const float* __restrict__ W,
                                                   float* __restrict__ C) {
    __shared__ float As[16][132];  // [k][m], transposed-A, +4 pad (float4-aligned)
    __shared__ float Bs[16][68];   // [k][n]
    const int n0 = blockIdx.x * 64;
    const int m0 = blockIdx.y * 128;
    const int tid = threadIdx.x;
    const int ty = tid >> 4, tx = tid & 15;
    const int ra = tid >> 2;        // 0..63 (A rows; also +64)
    const int ka = (tid & 3) * 4;   // 0,4,8,12
    const int kb = tid >> 4;        // 0..15
    const int nb = (tid & 15) * 4;

    float acc[8][4];
#pragma unroll
    for (int i = 0; i < 8; ++i) {
        acc[i][0] = 0.f; acc[i][1] = 0.f; acc[i][2] = 0.f; acc[i][3] = 0.f;
    }

    for (int k0 = 0; k0 < D; k0 += 16) {
        float4 a0 = *reinterpret_cast<const float4*>(&X[(size_t)(m0 + ra) * D + k0 + ka]);
        float4 a1 = *reinterpret_cast<const float4*>(&X[(size_t)(m0 + ra + 64) * D + k0 + ka]);
        float4 wb = *reinterpret_cast<const float4*>(&W[(size_t)(k0 + kb) * D + n0 + nb]);
        As[ka][ra] = a0.x; As[ka + 1][ra] = a0.y; As[ka + 2][ra] = a0.z; As[ka + 3][ra] = a0.w;
        As[ka][ra + 64] = a1.x; As[ka + 1][ra + 64] = a1.y;
        As[ka + 2][ra + 64] = a1.z; As[ka + 3][ra + 64] = a1.w;
        *reinterpret_cast<float4*>(&Bs[kb][nb]) = wb;
        __syncthreads();
#pragma unroll
        for (int kk = 0; kk < 16; ++kk) {
            float4 a04 = *reinterpret_cast<const float4*>(&As[kk][ty * 8]);
            float4 a14 = *reinterpret_cast<const float4*>(&As[kk][ty * 8 + 4]);
            float4 b4  = *reinterpret_cast<const float4*>(&Bs[kk][tx * 4]);
            const float av[8] = {a04.x, a04.y, a04.z, a04.w, a14.x, a14.y, a14.z, a14.w};
            const float bv[4] = {b4.x, b4.y, b4.z, b4.w};
#pragma unroll
            for (int i = 0; i < 8; ++i)
#pragma unroll
                for (int j = 0; j < 4; ++j)
                    acc[i][j] += av[i] * bv[j];
        }
        __syncthreads();
    }
#pragma unroll
    for (int i = 0; i < 8; ++i) {
        float4 v = make_float4(acc[i][0], acc[i][1], acc[i][2], acc[i][3]);
        *reinterpret_cast<float4*>(&C[(size_t)(m0 + ty * 8 + i) * D + n0 + tx * 4]) = v;
    }
}

// ---------------- fallback: naive sequential matvec (safety net) ----------------
__global__ void matvec_rowdot(const float* __restrict__ A, const float* __restrict__ y,
                              float* __restrict__ out) {
    const int wave = threadIdx.x >> 6, lane = threadIdx.x & 63;
    const int row = blockIdx.x * 4 + wave;
    const float* ar = A + (size_t)row * D;
    float s = 0.f;
#pragma unroll 8
    for (int k = lane; k < D; k += 64) s += ar[k] * y[k];
#pragma unroll
    for (int off = 32; off; off >>= 1) s += __shfl_down(s, off);
    if (lane == 0) out[row] = s;
}

extern "C" void kernel_launch(void* const* d_in, const int* in_sizes, int n_in,
                              void* d_out, int out_size, void* d_ws, size_t ws_size,
                              hipStream_t stream) {
    const float* A      = (const float*)d_in[0];  // [D][D]
    const float* y_init = (const float*)d_in[1];  // [2][D]; row 0 is the seed
    float* out = (float*)d_out;                   // [STEPS][D]

    const size_t matB = (size_t)D * D * sizeof(float);
    if (ws_size >= 2 * matB) {
        float* Pa = (float*)d_ws;          // power ping
        float* Pb = Pa + (size_t)D * D;    // power pong

        // T = A^T
        transpose_k<<<dim3(D / 32, D / 32), dim3(32, 8), 0, stream>>>(A, Pa);

        // rows[0] = y1 · T
        gemm_rows<<<dim3(D / 64, 1), 256, 0, stream>>>(y_init, Pa, out, 1);

        // doubling: m = 1,2,...,KB/2 ; after loop cur = T^KB
        float* cur = Pa;
        float* nxt = Pb;
        for (int m = 1; m < KB; m <<= 1) {
            gemm_rows<<<dim3(D / 64, (m + 31) / 32), 256, 0, stream>>>(
                out, cur, out + (size_t)m * D, m);
            gemm_big<<<dim3(D / 64, D / 128), 256, 0, stream>>>(cur, cur, nxt);
            float* t = cur; cur = nxt; nxt = t;
        }

        // chain: rows[j*KB ..) = rows[(j-1)*KB ..) · T^KB
        for (int j = 1; j < STEPS / KB; ++j) {
            gemm_rows<<<dim3(D / 64, KB / 32), 256, 0, stream>>>(
                out + (size_t)(j - 1) * KB * D, cur, out + (size_t)j * KB * D, KB);
        }
    } else {
        // workspace too small: correct-but-slow sequential matvec chain
        matvec_rowdot<<<D / 4, 256, 0, stream>>>(A, y_init, out);
        for (int t = 1; t < STEPS; ++t)
            matvec_rowdot<<<D / 4, 256, 0, stream>>>(A, out + (size_t)(t - 1) * D,
                                                     out + (size_t)t * D);
    }
}

// Round 2
// 3047.859 us; speedup vs baseline: 1.7634x; 1.7634x over previous
//
#include <hip/hip_runtime.h>

// LinearRNN: ys[t] = A^(t+1) @ y_init[0], t = 0..8191, D = 2048.
// Row-vector convention: T = A^T, rows[t] = y1 · T^(t+1).
// MFMA path: every fp32 value split into 3 bf16 limbs (h,m,l); GEMM computes the
// 6 significant limb products on the 16x16x32 bf16 matrix core (error ~ fp32).
// Schedule: 10 squarings (T^2..T^1024) + doubling rows[0..1024) + 7 chain GEMMs
// of M=1024. Powers kept in row-split (A-operand) and col-split (B-operand) form.

#define D 2048
#define STEPS 8192

typedef __attribute__((ext_vector_type(8))) short short8;
typedef __attribute__((ext_vector_type(4))) float f32x4;
typedef __attribute__((ext_vector_type(4))) unsigned short ushort4v;
typedef unsigned short ushort;

__device__ __forceinline__ ushort bf16_rne(float v) {
    unsigned u = __builtin_bit_cast(unsigned, v);
    u += 0x7fffu + ((u >> 16) & 1u);
    return (ushort)(u >> 16);
}
__device__ __forceinline__ float bf16_to_f(ushort h) {
    unsigned u = (unsigned)h << 16;
    return __builtin_bit_cast(float, u);
}

// ---------------- prep: A -> norm-split of T (=A^T) and trans-split (=A) ----------------
__global__ __launch_bounds__(256) void prep_T(const float* __restrict__ A,
    ushort* __restrict__ Nh, ushort* __restrict__ Nm, ushort* __restrict__ Nl,
    ushort* __restrict__ Uh, ushort* __restrict__ Um, ushort* __restrict__ Ul) {
    __shared__ float t[32][33];
    const int tx = threadIdx.x, ty = threadIdx.y;  // (32,8)
    const int bx = blockIdx.x * 32, by = blockIdx.y * 32;
#pragma unroll
    for (int i = 0; i < 4; ++i) {
        const int r = by + ty + i * 8;
        const float x = A[(size_t)r * D + bx + tx];
        t[ty + i * 8][tx] = x;
        const ushort h = bf16_rne(x);
        const float r1 = x - bf16_to_f(h);
        const ushort md = bf16_rne(r1);
        const float r2 = r1 - bf16_to_f(md);
        const ushort lo = bf16_rne(r2);
        const size_t o = (size_t)r * D + bx + tx;   // U = straight split of A
        Uh[o] = h; Um[o] = md; Ul[o] = lo;
    }
    __syncthreads();
#pragma unroll
    for (int i = 0; i < 4; ++i) {
        const float x = t[tx][ty + i * 8];          // = A[by+tx][bx+ty+i*8]
        const ushort h = bf16_rne(x);
        const float r1 = x - bf16_to_f(h);
        const ushort md = bf16_rne(r1);
        const float r2 = r1 - bf16_to_f(md);
        const ushort lo = bf16_rne(r2);
        const size_t o = (size_t)(bx + ty + i * 8) * D + by + tx;  // N[r][k] = A[k][r]
        Nh[o] = h; Nm[o] = md; Nl[o] = lo;
    }
}

// ---------------- bf16 transpose of a split triple (scheme B: col-split -> row-split) ----
__global__ __launch_bounds__(256) void transpose3(
    const ushort* __restrict__ Sh, const ushort* __restrict__ Sm, const ushort* __restrict__ Sl,
    ushort* __restrict__ Dh, ushort* __restrict__ Dm, ushort* __restrict__ Dl) {
    __shared__ ushort t[3][32][33];
    const int tx = threadIdx.x, ty = threadIdx.y;
    const int bx = blockIdx.x * 32, by = blockIdx.y * 32;
#pragma unroll
    for (int i = 0; i < 4; ++i) {
        const size_t o = (size_t)(by + ty + i * 8) * D + bx + tx;
        t[0][ty + i * 8][tx] = Sh[o];
        t[1][ty + i * 8][tx] = Sm[o];
        t[2][ty + i * 8][tx] = Sl[o];
    }
    __syncthreads();
#pragma unroll
    for (int i = 0; i < 4; ++i) {
        const size_t o = (size_t)(bx + ty + i * 8) * D + by + tx;
        Dh[o] = t[0][tx][ty + i * 8];
        Dm[o] = t[1][tx][ty + i * 8];
        Dl[o] = t[2][tx][ty + i * 8];
    }
}

// ---------------- split y row 0 ----------------
__global__ void split_vec(const float* __restrict__ y,
                          ushort* __restrict__ h, ushort* __restrict__ m, ushort* __restrict__ l) {
    const int i = blockIdx.x * 256 + threadIdx.x;
    if (i < D) {
        const float x = y[i];
        const ushort hh = bf16_rne(x);
        const float r1 = x - bf16_to_f(hh);
        const ushort mm = bf16_rne(r1);
        const float r2 = r1 - bf16_to_f(mm);
        h[i] = hh; m[i] = mm; l[i] = bf16_rne(r2);
    }
}

// ---------------- split-bf16 MFMA GEMM: C[M][2048] = X · W ----------------
// X row-split triple (X*[r][k]); W col-split triple (W*[c][k] holds W[k][c]).
// Outputs (templated): fp32 C, row-split of C (N*), col-split of C (U*[c][r]).
// Tile 128x128, BK=32, 4 waves; 6 MFMA products per fragment position.
template<bool WF32, bool WNORM, bool WTRANS>
__global__ __launch_bounds__(256, 2) void gemm3(
    const ushort* __restrict__ Xh, const ushort* __restrict__ Xm, const ushort* __restrict__ Xl,
    const ushort* __restrict__ Wh, const ushort* __restrict__ Wm, const ushort* __restrict__ Wl,
    float* __restrict__ Cf,
    ushort* __restrict__ Nh, ushort* __restrict__ Nm, ushort* __restrict__ Nl,
    ushort* __restrict__ Uh, ushort* __restrict__ Um, ushort* __restrict__ Ul,
    int M) {
    __shared__ __align__(16) ushort lds[6][128][32];  // 0..2 = X h/m/l, 3..5 = W h/m/l
    const int tid = threadIdx.x;
    const int w = tid >> 6, lane = tid & 63;

    // XCD-aware swizzle (all grids have nwg % 8 == 0)
    const int gx = gridDim.x;
    const int nwg = gx * gridDim.y;
    int id = blockIdx.y * gx + blockIdx.x;
    if ((nwg & 7) == 0) { const int cpx = nwg >> 3; id = (id & 7) * cpx + (id >> 3); }
    const int n0 = (id % gx) * 128;
    const int m0 = (id / gx) * 128;

    const int wr = (w >> 1) * 64, wc = (w & 1) * 64;

    // staging descriptors: 12 passes per thread (48 total: 6 tiles x 8 sub-rows)
    const ushort* gsrc[12];
    int ldsb[12];
#pragma unroll
    for (int s = 0; s < 12; ++s) {
        const int p = w + 4 * s;          // 0..47
        const int t = p >> 3;             // tile
        const int sub = p & 7;
        const int row = sub * 16 + (lane >> 2);
        const int gs = lane & 3;
        const int sl = gs ^ (row & 3);    // XOR swizzle (write side)
        ldsb[s] = t * 8192 + row * 64 + sl * 16;
        if (t < 3) {
            const int rg = min(m0 + row, M - 1);
            const ushort* base = (t == 0) ? Xh : (t == 1) ? Xm : Xl;
            gsrc[s] = base + (size_t)rg * D + gs * 8;
        } else {
            const int rg = n0 + row;
            const ushort* base = (t == 3) ? Wh : (t == 4) ? Wm : Wl;
            gsrc[s] = base + (size_t)rg * D + gs * 8;
        }
    }

    // fragment LDS byte offsets (constant across k-steps), XOR swizzle (read side)
    int aoff[4], boff[4];
#pragma unroll
    for (int q = 0; q < 4; ++q) {
        const int ar = wr + q * 16 + (lane & 15);
        aoff[q] = ar * 64 + (((lane >> 4) ^ (ar & 3)) * 16);
        const int br = wc + q * 16 + (lane & 15);
        boff[q] = br * 64 + (((lane >> 4) ^ (br & 3)) * 16);
    }

    f32x4 acc[4][4] = {};
    char* ldsc = (char*)lds;

    short8 st[12];
#pragma unroll
    for (int s = 0; s < 12; ++s) st[s] = *(const short8*)(gsrc[s]);

    for (int k0 = 32; k0 <= 2048; k0 += 32) {
        __syncthreads();  // previous compute done, LDS free
#pragma unroll
        for (int s = 0; s < 12; ++s) *(short8*)(ldsc + ldsb[s]) = st[s];
        __syncthreads();  // LDS ready
        if (k0 < 2048) {  // prefetch next k-step; latency hides under MFMAs below
#pragma unroll
            for (int s = 0; s < 12; ++s) st[s] = *(const short8*)(gsrc[s] + k0);
        }
        short8 af[3][4];
#pragma unroll
        for (int L = 0; L < 3; ++L)
#pragma unroll
            for (int q = 0; q < 4; ++q)
                af[L][q] = *(const short8*)(ldsc + L * 8192 + aoff[q]);
#pragma unroll
        for (int nr = 0; nr < 4; ++nr) {
            short8 b0 = *(const short8*)(ldsc + 3 * 8192 + boff[nr]);
            short8 b1 = *(const short8*)(ldsc + 4 * 8192 + boff[nr]);
            short8 b2 = *(const short8*)(ldsc + 5 * 8192 + boff[nr]);
#pragma unroll
            for (int mr = 0; mr < 4; ++mr) {
                f32x4 t = acc[mr][nr];
                t = __builtin_amdgcn_mfma_f32_16x16x32_bf16(af[2][mr], b0, t, 0, 0, 0);  // l*h
                t = __builtin_amdgcn_mfma_f32_16x16x32_bf16(af[1][mr], b1, t, 0, 0, 0);  // m*m
                t = __builtin_amdgcn_mfma_f32_16x16x32_bf16(af[0][mr], b2, t, 0, 0, 0);  // h*l
                t = __builtin_amdgcn_mfma_f32_16x16x32_bf16(af[1][mr], b0, t, 0, 0, 0);  // m*h
                t = __builtin_amdgcn_mfma_f32_16x16x32_bf16(af[0][mr], b1, t, 0, 0, 0);  // h*m
                t = __builtin_amdgcn_mfma_f32_16x16x32_bf16(af[0][mr], b0, t, 0, 0, 0);  // h*h
                acc[mr][nr] = t;
            }
        }
    }

    // epilogue: C/D layout col = lane&15, row = (lane>>4)*4 + j  [verified]
    const int lr = lane >> 4, lc = lane & 15;
    const int col0 = n0 + wc + lc;
    const int row0 = m0 + wr + lr * 4;
#pragma unroll
    for (int mr = 0; mr < 4; ++mr) {
#pragma unroll
        for (int nr = 0; nr < 4; ++nr) {
            const int c = col0 + nr * 16;
            const int rb = row0 + mr * 16;
            ushort hs[4], ms[4], ls[4];
#pragma unroll
            for (int j = 0; j < 4; ++j) {
                const float v = acc[mr][nr][j];
                const ushort h = bf16_rne(v);
                const float r1 = v - bf16_to_f(h);
                const ushort md = bf16_rne(r1);
                const float r2 = r1 - bf16_to_f(md);
                const ushort lo = bf16_rne(r2);
                hs[j] = h; ms[j] = md; ls[j] = lo;
                const int r = rb + j;
                if constexpr (WF32) { if (r < M) Cf[(size_t)r * D + c] = v; }
                if constexpr (WNORM) {
                    if (r < M) {
                        Nh[(size_t)r * D + c] = h;
                        Nm[(size_t)r * D + c] = md;
                        Nl[(size_t)r * D + c] = lo;
                    }
                }
            }
            if constexpr (WTRANS) {
                if (rb + 3 < M) {
                    ushort4v hv = {hs[0], hs[1], hs[2], hs[3]};
                    ushort4v mv = {ms[0], ms[1], ms[2], ms[3]};
                    ushort4v lv = {ls[0], ls[1], ls[2], ls[3]};
                    *(ushort4v*)&Uh[(size_t)c * D + rb] = hv;
                    *(ushort4v*)&Um[(size_t)c * D + rb] = mv;
                    *(ushort4v*)&Ul[(size_t)c * D + rb] = lv;
                }
            }
        }
    }
}

// ================= fp32 fallback (round-1, known-good) =================
__global__ void transpose_k(const float* __restrict__ A, float* __restrict__ T) {
    __shared__ float tile[32][33];
    const int bx = blockIdx.x * 32, by = blockIdx.y * 32;
    const int tx = threadIdx.x, ty = threadIdx.y;
#pragma unroll
    for (int i = 0; i < 32; i += 8)
        tile[ty + i][tx] = A[(size_t)(by + ty + i) * D + bx + tx];
    __syncthreads();
#pragma unroll
    for (int i = 0; i < 32; i += 8)
        T[(size_t)(bx + ty + i) * D + by + tx] = tile[tx][ty + i];
}

__global__ __launch_bounds__(256) void gemm_rows(const float* __restrict__ X,
                                                 const float* __restrict__ W,
                                                 float* __restrict__ C, int M) {
    __shared__ float As[16][34];
    __shared__ float Bs[16][68];
    const int n0 = blockIdx.x * 64;
    const int m0 = blockIdx.y * 32;
    const int tid = threadIdx.x;
    const int ty = tid >> 4, tx = tid & 15;
    const int rs = tid >> 3;
    const int ks = (tid & 7) * 2;
    const int rclamp = min(m0 + rs, M - 1);
    const int kb = tid >> 4;
    const int nb = (tid & 15) * 4;
    float acc[2][4] = {{0.f, 0.f, 0.f, 0.f}, {0.f, 0.f, 0.f, 0.f}};
    for (int k0 = 0; k0 < D; k0 += 16) {
        float2 xa = *reinterpret_cast<const float2*>(&X[(size_t)rclamp * D + k0 + ks]);
        float4 wb = *reinterpret_cast<const float4*>(&W[(size_t)(k0 + kb) * D + n0 + nb]);
        As[ks][rs] = xa.x;
        As[ks + 1][rs] = xa.y;
        *reinterpret_cast<float4*>(&Bs[kb][nb]) = wb;
        __syncthreads();
#pragma unroll
        for (int kk = 0; kk < 16; ++kk) {
            float2 a = *reinterpret_cast<const float2*>(&As[kk][ty * 2]);
            float4 b = *reinterpret_cast<const float4*>(&Bs[kk][tx * 4]);
            acc[0][0] += a.x * b.x; acc[0][1] += a.x * b.y;
            acc[0][2] += a.x * b.z; acc[0][3] += a.x * b.w;
            acc[1][0] += a.y * b.x; acc[1][1] += a.y * b.y;
            acc[1][2] += a.y * b.z; acc[1][3] += a.y * b.w;
        }
        __syncthreads();
    }
#pragma unroll
    for (int i = 0; i < 2; ++i) {
        const int m = m0 + ty * 2 + i;
        if (m < M) {
            float4 v = make_float4(acc[i][0], acc[i][1], acc[i][2], acc[i][3]);
            *reinterpret_cast<float4*>(&C[(size_t)m * D + n0 + tx * 4]) = v;
        }
    }
}

__global__ __launch_bounds__(256, 2) void gemm_big(const float* __restrict__ X,
                                                   const float* __restrict__ W,
                                                   float* __restrict__ C) {
    __shared__ float As[16][132];
    __shared__ float Bs[16][68];
    const int n0 = blockIdx.x * 64;
    const int m0 = blockIdx.y * 128;
    const int tid = threadIdx.x;
    const int ty = tid >> 4, tx = tid & 15;
    const int ra = tid >> 2;
    const int ka = (tid & 3) * 4;
    const int kb = tid >> 4;
    const int nb = (tid & 15) * 4;
    float acc[8][4];
#pragma unroll
    for (int i = 0; i < 8; ++i) { acc[i][0] = 0.f; acc[i][1] = 0.f; acc[i][2] = 0.f; acc[i][3] = 0.f; }
    for (int k0 = 0; k0 < D; k0 += 16) {
        float4 a0 = *reinterpret_cast<const float4*>(&X[(size_t)(m0 + ra) * D + k0 + ka]);
        float4 a1 = *reinterpret_cast<const float4*>(&X[(size_t)(m0 + ra + 64) * D + k0 + ka]);
        float4 wb = *reinterpret_cast<const float4*>(&W[(size_t)(k0 + kb) * D + n0 + nb]);
        As[ka][ra] = a0.x; As[ka + 1][ra] = a0.y; As[ka + 2][ra] = a0.z; As[ka + 3][ra] = a0.w;
        As[ka][ra + 64] = a1.x; As[ka + 1][ra + 64] = a1.y;
        As[ka + 2][ra + 64] = a1.z; As[ka + 3][ra + 64] = a1.w;
        *reinterpret_cast<float4*>(&Bs[kb][nb]) = wb;
        __syncthreads();
#pragma unroll
        for (int kk = 0; kk < 16; ++kk) {
            float4 a04 = *reinterpret_cast<const float4*>(&As[kk][ty * 8]);
            float4 a14 = *reinterpret_cast<const float4*>(&As[kk][ty * 8 + 4]);
            float4 b4  = *reinterpret_cast<const float4*>(&Bs[kk][tx * 4]);
            const float av[8] = {a04.x, a04.y, a04.z, a04.w, a14.x, a14.y, a14.z, a14.w};
            const float bv[4] = {b4.x, b4.y, b4.z, b4.w};
#pragma unroll
            for (int i = 0; i < 8; ++i)
#pragma unroll
                for (int j = 0; j < 4; ++j)
                    acc[i][j] += av[i] * bv[j];
        }
        __syncthreads();
    }
#pragma unroll
    for (int i = 0; i < 8; ++i) {
        float4 v = make_float4(acc[i][0], acc[i][1], acc[i][2], acc[i][3]);
        *reinterpret_cast<float4*>(&C[(size_t)(m0 + ty * 8 + i) * D + n0 + tx * 4]) = v;
    }
}

// ================= host =================
extern "C" void kernel_launch(void* const* d_in, const int* in_sizes, int n_in,
                              void* d_out, int out_size, void* d_ws, size_t ws_size,
                              hipStream_t stream) {
    const float* A = (const float*)d_in[0];
    const float* y_init = (const float*)d_in[1];
    float* out = (float*)d_out;

    const size_t matB = (size_t)D * D * 2;  // bf16 matrix bytes (8 MB)
    const size_t needA = 12 * matB + 6 * (size_t)1024 * D * 2 + 3 * 8192;  // ~126 MB
    const size_t needB = 9 * matB + 6 * (size_t)512 * D * 2 + 3 * 8192;    // ~88 MB

    if (ws_size >= needB) {
        const bool big = (ws_size >= needA);
        const int KBv = big ? 1024 : 512;
        const int lg = big ? 10 : 9;

        char* c = (char*)d_ws;
        auto carve = [&](size_t bytes) { char* r = c; c += bytes; return (ushort*)r; };
        ushort *PTh[2], *PTm[2], *PTl[2];   // col-split powers (B-operand)
        for (int v = 0; v < 2; ++v) { PTh[v] = carve(matB); PTm[v] = carve(matB); PTl[v] = carve(matB); }
        ushort *PNh[2], *PNm[2], *PNl[2];   // row-split powers (A-operand); scheme B uses [0] as scratch
        const int nlev = big ? 2 : 1;
        for (int v = 0; v < nlev; ++v) { PNh[v] = carve(matB); PNm[v] = carve(matB); PNl[v] = carve(matB); }
        const size_t ringB = (size_t)KBv * D * 2;
        ushort *rgH[2], *rgM[2], *rgL[2];
        for (int v = 0; v < 2; ++v) { rgH[v] = carve(ringB); rgM[v] = carve(ringB); rgL[v] = carve(ringB); }
        ushort* yH = carve(8192); ushort* yM = carve(8192); ushort* yL = carve(8192);

        // prep: PN[0] = row-split of T (=A^T), PT[0] = col-split of T (=A)
        prep_T<<<dim3(64, 64), dim3(32, 8), 0, stream>>>(A, PNh[0], PNm[0], PNl[0],
                                                         PTh[0], PTm[0], PTl[0]);
        split_vec<<<8, 256, 0, stream>>>(y_init, yH, yM, yL);

        // seed: rows[0] = y1 · T
        gemm3<true, true, false><<<dim3(16, 1), 256, 0, stream>>>(
            yH, yM, yL, PTh[0], PTm[0], PTl[0],
            out, rgH[0], rgM[0], rgL[0], nullptr, nullptr, nullptr, 1);

        int cur = 0;
        for (int i = 0; i < lg; ++i) {
            const int m = 1 << i;
            // rows[m..2m) = rows[0..m) · T^m
            gemm3<true, true, false><<<dim3(16, (m + 127) / 128), 256, 0, stream>>>(
                rgH[0], rgM[0], rgL[0], PTh[cur], PTm[cur], PTl[cur],
                out + (size_t)m * D,
                rgH[0] + (size_t)m * D, rgM[0] + (size_t)m * D, rgL[0] + (size_t)m * D,
                nullptr, nullptr, nullptr, m);
            // squaring T^m -> T^2m
            const ushort *xh, *xm, *xl;
            if (big) { xh = PNh[cur]; xm = PNm[cur]; xl = PNl[cur]; }
            else {
                if (i > 0)
                    transpose3<<<dim3(64, 64), dim3(32, 8), 0, stream>>>(
                        PTh[cur], PTm[cur], PTl[cur], PNh[0], PNm[0], PNl[0]);
                xh = PNh[0]; xm = PNm[0]; xl = PNl[0];
            }
            if (big && i < lg - 1) {
                gemm3<false, true, true><<<dim3(16, 16), 256, 0, stream>>>(
                    xh, xm, xl, PTh[cur], PTm[cur], PTl[cur], nullptr,
                    PNh[cur ^ 1], PNm[cur ^ 1], PNl[cur ^ 1],
                    PTh[cur ^ 1], PTm[cur ^ 1], PTl[cur ^ 1], 2048);
            } else {
                gemm3<false, false, true><<<dim3(16, 16), 256, 0, stream>>>(
                    xh, xm, xl, PTh[cur], PTm[cur], PTl[cur], nullptr,
                    nullptr, nullptr, nullptr,
                    PTh[cur ^ 1], PTm[cur ^ 1], PTl[cur ^ 1], 2048);
            }
            cur ^= 1;
        }

        // chain: rows[j*KB..(j+1)*KB) = rows[(j-1)*KB..) · T^KB
        const int nblk = STEPS / KBv;
        for (int j = 1; j < nblk; ++j) {
            const int a = (j - 1) & 1, b = j & 1;
            if (j < nblk - 1)
                gemm3<true, true, false><<<dim3(16, KBv / 128), 256, 0, stream>>>(
                    rgH[a], rgM[a], rgL[a], PTh[cur], PTm[cur], PTl[cur],
                    out + (size_t)j * KBv * D, rgH[b], rgM[b], rgL[b],
                    nullptr, nullptr, nullptr, KBv);
            else
                gemm3<true, false, false><<<dim3(16, KBv / 128), 256, 0, stream>>>(
                    rgH[a], rgM[a], rgL[a], PTh[cur], PTm[cur], PTl[cur],
                    out + (size_t)j * KBv * D, nullptr, nullptr, nullptr,
                    nullptr, nullptr, nullptr, KBv);
        }
    } else {
        // fp32 fallback (round-1 path, known-good)
        float* Pa = (float*)d_ws;
        float* Pb = Pa + (size_t)D * D;
        transpose_k<<<dim3(D / 32, D / 32), dim3(32, 8), 0, stream>>>(A, Pa);
        gemm_rows<<<dim3(D / 64, 1), 256, 0, stream>>>(y_init, Pa, out, 1);
        float* cur = Pa;
        float* nxt = Pb;
        for (int m = 1; m < 256; m <<= 1) {
            gemm_rows<<<dim3(D / 64, (m + 31) / 32), 256, 0, stream>>>(
                out, cur, out + (size_t)m * D, m);
            gemm_big<<<dim3(D / 64, D / 128), 256, 0, stream>>>(cur, cur, nxt);
            float* t = cur; cur = nxt; nxt = t;
        }
        for (int j = 1; j < STEPS / 256; ++j) {
            gemm_rows<<<dim3(D / 64, 256 / 32), 256, 0, stream>>>(
                out + (size_t)(j - 1) * 256 * D, cur, out + (size_t)j * 256 * D, 256);
        }
    }
}

// Round 3
// 2131.890 us; speedup vs baseline: 2.5211x; 1.4297x over previous
//
#include <hip/hip_runtime.h>

// LinearRNN: ys[t] = A^(t+1) @ y_init[0], t = 0..8191, D = 2048.
// Row-vector convention: T = A^T, rows[t] = y1 * T^(t+1).
// fp32 -> 3 bf16 limbs (h,m,l); 6 limb-product MFMAs (16x16x32) ~= fp32 GEMM.
// Schedule (KB=1024): 10 squarings (M=2048, 256 WGs) + doubling rows + 7 chain
// GEMMs (M=1024, BN=64 tile -> 256 WGs). Pipelined K-loop: global_load_lds(16B)
// into double-buffered LDS, counted vmcnt (never 0 in loop), raw s_barrier.

#define D 2048
#define STEPS 8192
#define KB 1024

typedef __attribute__((ext_vector_type(8))) short short8;
typedef __attribute__((ext_vector_type(4))) float f32x4;
typedef __attribute__((ext_vector_type(4))) unsigned short ushort4v;
typedef unsigned short ushort;

__device__ __forceinline__ ushort bf16_rne(float v) {
    unsigned u = __builtin_bit_cast(unsigned, v);
    u += 0x7fffu + ((u >> 16) & 1u);
    return (ushort)(u >> 16);
}
__device__ __forceinline__ float bf16_to_f(ushort h) {
    unsigned u = (unsigned)h << 16;
    return __builtin_bit_cast(float, u);
}

__device__ __forceinline__ void gload16(const void* g, void* l) {
    __builtin_amdgcn_global_load_lds(
        (const __attribute__((address_space(1))) unsigned int*)g,
        (__attribute__((address_space(3))) unsigned int*)l, 16, 0, 0);
}

template<int N> __device__ __forceinline__ void vmwait();
template<> __device__ __forceinline__ void vmwait<0>() { asm volatile("s_waitcnt vmcnt(0)" ::: "memory"); }
template<> __device__ __forceinline__ void vmwait<6>() { asm volatile("s_waitcnt vmcnt(6)" ::: "memory"); }
template<> __device__ __forceinline__ void vmwait<9>() { asm volatile("s_waitcnt vmcnt(9)" ::: "memory"); }
__device__ __forceinline__ void lgkm0() { asm volatile("s_waitcnt lgkmcnt(0)" ::: "memory"); }
__device__ __forceinline__ void barfence() {
    __builtin_amdgcn_sched_barrier(0);
    __builtin_amdgcn_s_barrier();
    __builtin_amdgcn_sched_barrier(0);
}

// ---------------- prep: A -> row-split of T (=A^T) and col-split of T (=A) ----------------
__global__ __launch_bounds__(256) void prep_T(const float* __restrict__ A,
    ushort* __restrict__ Nh, ushort* __restrict__ Nm, ushort* __restrict__ Nl,
    ushort* __restrict__ Uh, ushort* __restrict__ Um, ushort* __restrict__ Ul) {
    __shared__ float t[32][33];
    const int tx = threadIdx.x, ty = threadIdx.y;  // (32,8)
    const int bx = blockIdx.x * 32, by = blockIdx.y * 32;
#pragma unroll
    for (int i = 0; i < 4; ++i) {
        const int r = by + ty + i * 8;
        const float x = A[(size_t)r * D + bx + tx];
        t[ty + i * 8][tx] = x;
        const ushort h = bf16_rne(x);
        const float r1 = x - bf16_to_f(h);
        const ushort md = bf16_rne(r1);
        const float r2 = r1 - bf16_to_f(md);
        const ushort lo = bf16_rne(r2);
        const size_t o = (size_t)r * D + bx + tx;   // U = straight split of A (col-split of T)
        Uh[o] = h; Um[o] = md; Ul[o] = lo;
    }
    __syncthreads();
#pragma unroll
    for (int i = 0; i < 4; ++i) {
        const float x = t[tx][ty + i * 8];          // = A[by+tx][bx+ty+i*8]
        const ushort h = bf16_rne(x);
        const float r1 = x - bf16_to_f(h);
        const ushort md = bf16_rne(r1);
        const float r2 = r1 - bf16_to_f(md);
        const ushort lo = bf16_rne(r2);
        const size_t o = (size_t)(bx + ty + i * 8) * D + by + tx;  // N[r][k] = A[k][r]
        Nh[o] = h; Nm[o] = md; Nl[o] = lo;
    }
}

__global__ void split_vec(const float* __restrict__ y,
                          ushort* __restrict__ h, ushort* __restrict__ m, ushort* __restrict__ l) {
    const int i = blockIdx.x * 256 + threadIdx.x;
    if (i < D) {
        const float x = y[i];
        const ushort hh = bf16_rne(x);
        const float r1 = x - bf16_to_f(hh);
        const ushort mm = bf16_rne(r1);
        const float r2 = r1 - bf16_to_f(mm);
        h[i] = hh; m[i] = mm; l[i] = bf16_rne(r2);
    }
}

// ---------------- split-bf16 MFMA GEMM: C[M][2048] = X * W ----------------
// BN=128: 512 thr (8 waves, 2x4 wavegrid), squaring-class. BN=64: 256 thr (4 waves, 2x2).
// Per-wave output 64x32 (acc[4][2]). LDS double-buffered; global_load_lds with
// pre-swizzled global source (linear LDS dest); XOR swizzle on ds_read side.
template<int BN, bool WF32, bool WNORM, bool WTRANS>
__global__ __launch_bounds__((BN == 128 ? 512 : 256), 2)
void gemm3(const ushort* __restrict__ Xh, const ushort* __restrict__ Xm, const ushort* __restrict__ Xl,
           const ushort* __restrict__ Wh, const ushort* __restrict__ Wm, const ushort* __restrict__ Wl,
           float* __restrict__ Cf,
           ushort* __restrict__ Nh, ushort* __restrict__ Nm, ushort* __restrict__ Nl,
           ushort* __restrict__ Uh, ushort* __restrict__ Um, ushort* __restrict__ Ul,
           int M) {
    constexpr int BTS = (BN == 128) ? 8192 : 4096;   // B limb-tile bytes
    constexpr int BUF = 24576 + 3 * BTS;             // 49152 / 36864
    constexpr int NCH = (BN == 128) ? 6 : 9;         // gload16 per thread per step
    __shared__ __align__(16) char smem[2 * BUF];

    const int tid = threadIdx.x;
    const int w = tid >> 6, lane = tid & 63;

    // XCD-aware swizzle (every grid here has nwg % 8 == 0)
    const int gx = gridDim.x;
    const int nwg = gx * gridDim.y;
    int id = blockIdx.y * gx + blockIdx.x;
    { const int cpx = nwg >> 3; id = (id & 7) * cpx + (id >> 3); }
    const int n0 = (id % gx) * BN;
    const int m0 = (id / gx) * 128;

    const int wr = (BN == 128) ? ((w >> 2) * 64) : ((w >> 1) * 64);
    const int wc = (BN == 128) ? ((w & 3) * 32) : ((w & 1) * 32);

    // ---- staging descriptors: linear LDS chunks, pre-swizzled global k-group ----
    const ushort* gp[NCH];
    int lu[NCH];  // wave-uniform LDS byte base (HW adds lane*16)
    if constexpr (BN == 128) {
        const int r = tid >> 2, g = tid & 3;
        const int gq = (g ^ (r & 3)) * 8;
        const size_t ao = (size_t)min(m0 + r, M - 1) * D + gq;
        const size_t bo = (size_t)(n0 + r) * D + gq;
        gp[0] = Xh + ao; gp[1] = Xm + ao; gp[2] = Xl + ao;
        gp[3] = Wh + bo; gp[4] = Wm + bo; gp[5] = Wl + bo;
#pragma unroll
        for (int s = 0; s < 6; ++s) lu[s] = s * 8192 + w * 1024;
    } else {
#pragma unroll
        for (int s = 0; s < 6; ++s) {  // A: 3 tiles x 512 chunks, 2 chunks/tile/thread
            const int c = tid + 256 * s;
            const int r = (c >> 2) & 127, g = c & 3;
            const int gq = (g ^ (r & 3)) * 8;
            const ushort* base = (s < 2) ? Xh : (s < 4) ? Xm : Xl;
            gp[s] = base + (size_t)min(m0 + r, M - 1) * D + gq;
            lu[s] = w * 1024 + s * 4096;
        }
#pragma unroll
        for (int s = 0; s < 3; ++s) {  // B: 3 tiles x 256 chunks
            const int c = tid + 256 * s;
            const int r = (c >> 2) & 63, g = c & 3;
            const int gq = (g ^ (r & 3)) * 8;
            const ushort* base = (s == 0) ? Wh : (s == 1) ? Wm : Wl;
            gp[6 + s] = base + (size_t)(n0 + r) * D + gq;
            lu[6 + s] = 24576 + w * 1024 + s * 4096;
        }
    }

    // ---- fragment ds_read byte offsets (XOR swizzle, read side) ----
    int aoff[4], boff[2];
#pragma unroll
    for (int q = 0; q < 4; ++q) {
        const int ar = wr + q * 16 + (lane & 15);
        aoff[q] = ar * 64 + (((lane >> 4) ^ (ar & 3)) * 16);
    }
#pragma unroll
    for (int nr = 0; nr < 2; ++nr) {
        const int br = wc + nr * 16 + (lane & 15);
        boff[nr] = 24576 + br * 64 + (((lane >> 4) ^ (br & 3)) * 16);
    }

    f32x4 acc[4][2] = {};
    char* ldsc = (char*)smem;

    auto stage = [&](int off) {
#pragma unroll
        for (int i = 0; i < NCH; ++i) { gload16(gp[i], ldsc + off + lu[i]); gp[i] += 32; }
    };
    auto compute = [&](int off) {
        short8 af[3][4], bf[3][2];
#pragma unroll
        for (int L = 0; L < 3; ++L) {
#pragma unroll
            for (int q = 0; q < 4; ++q)
                af[L][q] = *(const short8*)(ldsc + off + L * 8192 + aoff[q]);
#pragma unroll
            for (int nr = 0; nr < 2; ++nr)
                bf[L][nr] = *(const short8*)(ldsc + off + L * BTS + boff[nr]);
        }
        // product-major (ascending magnitude): 8 independent MFMAs per product
#define PROD(La, Lb) \
        _Pragma("unroll") \
        for (int q = 0; q < 4; ++q) { \
            acc[q][0] = __builtin_amdgcn_mfma_f32_16x16x32_bf16(af[La][q], bf[Lb][0], acc[q][0], 0, 0, 0); \
            acc[q][1] = __builtin_amdgcn_mfma_f32_16x16x32_bf16(af[La][q], bf[Lb][1], acc[q][1], 0, 0, 0); \
        }
        PROD(2, 0) PROD(1, 1) PROD(0, 2) PROD(1, 0) PROD(0, 1) PROD(0, 0)
#undef PROD
    };

    // ---- pipelined K-loop: 64 steps of BK=32, 2-buffer ring, counted vmcnt ----
    stage(0);
    for (int t = 0; t < 63; ++t) {
        stage(((t + 1) & 1) * BUF);   // buffer freed by trailing barrier of t-1
        vmwait<NCH>();                // stage(t) landed; stage(t+1) stays in flight
        barfence();
        compute((t & 1) * BUF);
        lgkm0();
        barfence();
    }
    vmwait<0>();
    barfence();
    compute(BUF);                     // t = 63

    // ---- epilogue: C/D layout col=lane&15, row=(lane>>4)*4+j (verified) ----
    const int lc = lane & 15;
    const int col0 = n0 + wc + lc;
    const int row0 = m0 + wr + (lane >> 4) * 4;
#pragma unroll
    for (int q = 0; q < 4; ++q) {
#pragma unroll
        for (int nr = 0; nr < 2; ++nr) {
            const int c = col0 + nr * 16;
            const int rbse = row0 + q * 16;
            ushort hs[4], ms[4], ls[4];
#pragma unroll
            for (int j = 0; j < 4; ++j) {
                const float v = acc[q][nr][j];
                const ushort h = bf16_rne(v);
                const float r1 = v - bf16_to_f(h);
                const ushort md = bf16_rne(r1);
                const float r2 = r1 - bf16_to_f(md);
                const ushort lo = bf16_rne(r2);
                hs[j] = h; ms[j] = md; ls[j] = lo;
                const int r = rbse + j;
                if constexpr (WF32) { if (r < M) Cf[(size_t)r * D + c] = v; }
                if constexpr (WNORM) {
                    if (r < M) {
                        Nh[(size_t)r * D + c] = h;
                        Nm[(size_t)r * D + c] = md;
                        Nl[(size_t)r * D + c] = lo;
                    }
                }
            }
            if constexpr (WTRANS) {
                if (rbse + 3 < M) {
                    ushort4v hv = {hs[0], hs[1], hs[2], hs[3]};
                    ushort4v mv = {ms[0], ms[1], ms[2], ms[3]};
                    ushort4v lv = {ls[0], ls[1], ls[2], ls[3]};
                    *(ushort4v*)&Uh[(size_t)c * D + rbse] = hv;
                    *(ushort4v*)&Um[(size_t)c * D + rbse] = mv;
                    *(ushort4v*)&Ul[(size_t)c * D + rbse] = lv;
                }
            }
        }
    }
}

// ================= fp32 fallback (round-1, known-good) =================
__global__ void transpose_k(const float* __restrict__ A, float* __restrict__ T) {
    __shared__ float tile[32][33];
    const int bx = blockIdx.x * 32, by = blockIdx.y * 32;
    const int tx = threadIdx.x, ty = threadIdx.y;
#pragma unroll
    for (int i = 0; i < 32; i += 8)
        tile[ty + i][tx] = A[(size_t)(by + ty + i) * D + bx + tx];
    __syncthreads();
#pragma unroll
    for (int i = 0; i < 32; i += 8)
        T[(size_t)(bx + ty + i) * D + by + tx] = tile[tx][ty + i];
}

__global__ __launch_bounds__(256) void gemm_rows(const float* __restrict__ X,
                                                 const float* __restrict__ W,
                                                 float* __restrict__ C, int M) {
    __shared__ float As[16][34];
    __shared__ float Bs[16][68];
    const int n0 = blockIdx.x * 64;
    const int m0 = blockIdx.y * 32;
    const int tid = threadIdx.x;
    const int ty = tid >> 4, tx = tid & 15;
    const int rs = tid >> 3;
    const int ks = (tid & 7) * 2;
    const int rclamp = min(m0 + rs, M - 1);
    const int kb = tid >> 4;
    const int nb = (tid & 15) * 4;
    float acc[2][4] = {{0.f, 0.f, 0.f, 0.f}, {0.f, 0.f, 0.f, 0.f}};
    for (int k0 = 0; k0 < D; k0 += 16) {
        float2 xa = *reinterpret_cast<const float2*>(&X[(size_t)rclamp * D + k0 + ks]);
        float4 wb = *reinterpret_cast<const float4*>(&W[(size_t)(k0 + kb) * D + n0 + nb]);
        As[ks][rs] = xa.x;
        As[ks + 1][rs] = xa.y;
        *reinterpret_cast<float4*>(&Bs[kb][nb]) = wb;
        __syncthreads();
#pragma unroll
        for (int kk = 0; kk < 16; ++kk) {
            float2 a = *reinterpret_cast<const float2*>(&As[kk][ty * 2]);
            float4 b = *reinterpret_cast<const float4*>(&Bs[kk][tx * 4]);
            acc[0][0] += a.x * b.x; acc[0][1] += a.x * b.y;
            acc[0][2] += a.x * b.z; acc[0][3] += a.x * b.w;
            acc[1][0] += a.y * b.x; acc[1][1] += a.y * b.y;
            acc[1][2] += a.y * b.z; acc[1][3] += a.y * b.w;
        }
        __syncthreads();
    }
#pragma unroll
    for (int i = 0; i < 2; ++i) {
        const int m = m0 + ty * 2 + i;
        if (m < M) {
            float4 v = make_float4(acc[i][0], acc[i][1], acc[i][2], acc[i][3]);
            *reinterpret_cast<float4*>(&C[(size_t)m * D + n0 + tx * 4]) = v;
        }
    }
}

__global__ __launch_bounds__(256, 2) void gemm_big(const float* __restrict__ X,
                                                   const float* __restrict__ W,
                                                   float* __restrict__ C) {
    __shared__ float As[16][132];
    __shared__ float Bs[16][68];
    const int n0 = blockIdx.x * 64;
    const int m0 = blockIdx.y * 128;
    const int tid = threadIdx.x;
    const int ty = tid >> 4, tx = tid & 15;
    const int ra = tid >> 2;
    const int ka = (tid & 3) * 4;
    const int kb = tid >> 4;
    const int nb = (tid & 15) * 4;
    float acc[8][4];
#pragma unroll
    for (int i = 0; i < 8; ++i) { acc[i][0] = 0.f; acc[i][1] = 0.f; acc[i][2] = 0.f; acc[i][3] = 0.f; }
    for (int k0 = 0; k0 < D; k0 += 16) {
        float4 a0 = *reinterpret_cast<const float4*>(&X[(size_t)(m0 + ra) * D + k0 + ka]);
        float4 a1 = *reinterpret_cast<const float4*>(&X[(size_t)(m0 + ra + 64) * D + k0 + ka]);
        float4 wb = *reinterpret_cast<const float4*>(&W[(size_t)(k0 + kb) * D + n0 + nb]);
        As[ka][ra] = a0.x; As[ka + 1][ra] = a0.y; As[ka + 2][ra] = a0.z; As[ka + 3][ra] = a0.w;
        As[ka][ra + 64] = a1.x; As[ka + 1][ra + 64] = a1.y;
        As[ka + 2][ra + 64] = a1.z; As[ka + 3][ra + 64] = a1.w;
        *reinterpret_cast<float4*>(&Bs[kb][nb]) = wb;
        __syncthreads();
#pragma unroll
        for (int kk = 0; kk < 16; ++kk) {
            float4 a04 = *reinterpret_cast<const float4*>(&As[kk][ty * 8]);
            float4 a14 = *reinterpret_cast<const float4*>(&As[kk][ty * 8 + 4]);
            float4 b4  = *reinterpret_cast<const float4*>(&Bs[kk][tx * 4]);
            const float av[8] = {a04.x, a04.y, a04.z, a04.w, a14.x, a14.y, a14.z, a14.w};
            const float bv[4] = {b4.x, b4.y, b4.z, b4.w};
#pragma unroll
            for (int i = 0; i < 8; ++i)
#pragma unroll
                for (int j = 0; j < 4; ++j)
                    acc[i][j] += av[i] * bv[j];
        }
        __syncthreads();
    }
#pragma unroll
    for (int i = 0; i < 8; ++i) {
        float4 v = make_float4(acc[i][0], acc[i][1], acc[i][2], acc[i][3]);
        *reinterpret_cast<float4*>(&C[(size_t)(m0 + ty * 8 + i) * D + n0 + tx * 4]) = v;
    }
}

__global__ void matvec_rowdot(const float* __restrict__ A, const float* __restrict__ y,
                              float* __restrict__ out) {
    const int wave = threadIdx.x >> 6, lane = threadIdx.x & 63;
    const int row = blockIdx.x * 4 + wave;
    const float* ar = A + (size_t)row * D;
    float s = 0.f;
#pragma unroll 8
    for (int k = lane; k < D; k += 64) s += ar[k] * y[k];
#pragma unroll
    for (int off = 32; off; off >>= 1) s += __shfl_down(s, off);
    if (lane == 0) out[row] = s;
}

// ================= host =================
extern "C" void kernel_launch(void* const* d_in, const int* in_sizes, int n_in,
                              void* d_out, int out_size, void* d_ws, size_t ws_size,
                              hipStream_t stream) {
    const float* A = (const float*)d_in[0];
    const float* y_init = (const float*)d_in[1];
    float* out = (float*)d_out;

    const size_t matB = (size_t)D * D * 2;                                // 8 MB
    const size_t ringB = (size_t)KB * D * 2;                              // 4 MB
    const size_t needA = 12 * matB + 6 * ringB + 3 * 8192;

    if (ws_size >= needA) {
        char* c = (char*)d_ws;
        auto carve = [&](size_t bytes) { char* r = c; c += bytes; return (ushort*)r; };
        ushort *PTh[2], *PTm[2], *PTl[2];   // col-split powers (B-operand)
        for (int v = 0; v < 2; ++v) { PTh[v] = carve(matB); PTm[v] = carve(matB); PTl[v] = carve(matB); }
        ushort *PNh[2], *PNm[2], *PNl[2];   // row-split powers (A-operand)
        for (int v = 0; v < 2; ++v) { PNh[v] = carve(matB); PNm[v] = carve(matB); PNl[v] = carve(matB); }
        ushort *rgH[2], *rgM[2], *rgL[2];   // row-split ys ring (KB rows)
        for (int v = 0; v < 2; ++v) { rgH[v] = carve(ringB); rgM[v] = carve(ringB); rgL[v] = carve(ringB); }
        ushort* yH = carve(8192); ushort* yM = carve(8192); ushort* yL = carve(8192);

        prep_T<<<dim3(64, 64), dim3(32, 8), 0, stream>>>(A, PNh[0], PNm[0], PNl[0],
                                                         PTh[0], PTm[0], PTl[0]);
        split_vec<<<8, 256, 0, stream>>>(y_init, yH, yM, yL);

        // seed: rows[0] = y1 * T
        gemm3<64, true, true, false><<<dim3(32, 1), 256, 0, stream>>>(
            yH, yM, yL, PTh[0], PTm[0], PTl[0],
            out, rgH[0], rgM[0], rgL[0], nullptr, nullptr, nullptr, 1);

        int cur = 0;
        for (int i = 0; i < 10; ++i) {
            const int m = 1 << i;
            // doubling: rows[m..2m) = rows[0..m) * T^m
            gemm3<64, true, true, false><<<dim3(32, (m + 127) / 128), 256, 0, stream>>>(
                rgH[0], rgM[0], rgL[0], PTh[cur], PTm[cur], PTl[cur],
                out + (size_t)m * D,
                rgH[0] + (size_t)m * D, rgM[0] + (size_t)m * D, rgL[0] + (size_t)m * D,
                nullptr, nullptr, nullptr, m);
            // squaring: T^m -> T^2m (row-split + col-split outputs; last needs col only)
            if (i < 9)
                gemm3<128, false, true, true><<<dim3(16, 16), 512, 0, stream>>>(
                    PNh[cur], PNm[cur], PNl[cur], PTh[cur], PTm[cur], PTl[cur], nullptr,
                    PNh[cur ^ 1], PNm[cur ^ 1], PNl[cur ^ 1],
                    PTh[cur ^ 1], PTm[cur ^ 1], PTl[cur ^ 1], 2048);
            else
                gemm3<128, false, false, true><<<dim3(16, 16), 512, 0, stream>>>(
                    PNh[cur], PNm[cur], PNl[cur], PTh[cur], PTm[cur], PTl[cur], nullptr,
                    nullptr, nullptr, nullptr,
                    PTh[cur ^ 1], PTm[cur ^ 1], PTl[cur ^ 1], 2048);
            cur ^= 1;
        }

        // chain: rows[j*KB..(j+1)*KB) = rows[(j-1)*KB..) * T^KB  (grid 32x8 = 256 WGs)
        for (int j = 1; j < STEPS / KB; ++j) {
            const int a = (j - 1) & 1, b = j & 1;
            if (j < STEPS / KB - 1)
                gemm3<64, true, true, false><<<dim3(32, KB / 128), 256, 0, stream>>>(
                    rgH[a], rgM[a], rgL[a], PTh[cur], PTm[cur], PTl[cur],
                    out + (size_t)j * KB * D, rgH[b], rgM[b], rgL[b],
                    nullptr, nullptr, nullptr, KB);
            else
                gemm3<64, true, false, false><<<dim3(32, KB / 128), 256, 0, stream>>>(
                    rgH[a], rgM[a], rgL[a], PTh[cur], PTm[cur], PTl[cur],
                    out + (size_t)j * KB * D, nullptr, nullptr, nullptr,
                    nullptr, nullptr, nullptr, KB);
        }
    } else if (ws_size >= 2 * (size_t)D * D * sizeof(float)) {
        // fp32 fallback (round-1 path, known-good)
        float* Pa = (float*)d_ws;
        float* Pb = Pa + (size_t)D * D;
        transpose_k<<<dim3(D / 32, D / 32), dim3(32, 8), 0, stream>>>(A, Pa);
        gemm_rows<<<dim3(D / 64, 1), 256, 0, stream>>>(y_init, Pa, out, 1);
        float* cur = Pa;
        float* nxt = Pb;
        for (int m = 1; m < 256; m <<= 1) {
            gemm_rows<<<dim3(D / 64, (m + 31) / 32), 256, 0, stream>>>(
                out, cur, out + (size_t)m * D, m);
            gemm_big<<<dim3(D / 64, D / 128), 256, 0, stream>>>(cur, cur, nxt);
            float* t = cur; cur = nxt; nxt = t;
        }
        for (int j = 1; j < STEPS / 256; ++j) {
            gemm_rows<<<dim3(D / 64, 256 / 32), 256, 0, stream>>>(
                out + (size_t)(j - 1) * 256 * D, cur, out + (size_t)j * 256 * D, 256);
        }
    } else {
        matvec_rowdot<<<D / 4, 256, 0, stream>>>(A, y_init, out);
        for (int t = 1; t < STEPS; ++t)
            matvec_rowdot<<<D / 4, 256, 0, stream>>>(A, out + (size_t)(t - 1) * D,
                                                     out + (size_t)t * D);
    }
}

// Round 4
// 1785.483 us; speedup vs baseline: 3.0102x; 1.1940x over previous
//
#include <hip/hip_runtime.h>

// LinearRNN: ys[t] = A^(t+1) @ y_init[0], t = 0..8191, D = 2048.
// Row-vector convention: T = A^T, rows[t] = y1 * T^(t+1).
// fp32 -> 3 bf16 limbs (h,m,l); 6 limb-product MFMAs (16x16x32) ~= fp32 GEMM.
// This round: FRAGMENT-PACKED operand layouts. A-operand (PA) and B-operand (PB)
// live in global memory in MFMA fragment order (1KB per 16x32 fragment = 64
// lanes x 16B). Staging is linear global_load_lds; ds_read_b128 is
// frag_base + lane*16 -> zero bank conflicts, no swizzle anywhere.
// Tile 128x64, 512 thr (8 waves, 4Mx2N, wave tile 32x32), BK=32, LDS 72KB
// double-buffered -> 2 blocks/CU. Counted vmcnt staging + setprio on MFMAs.

#define D 2048
#define STEPS 8192
#define KB 1024

typedef __attribute__((ext_vector_type(8))) short short8;
typedef __attribute__((ext_vector_type(4))) float f32x4;
typedef __attribute__((ext_vector_type(4))) unsigned short ushort4v;
typedef __attribute__((ext_vector_type(8))) unsigned short ushort8v;
typedef unsigned short ushort;

__device__ __forceinline__ ushort bf16_rne(float v) {
    unsigned u = __builtin_bit_cast(unsigned, v);
    u += 0x7fffu + ((u >> 16) & 1u);
    return (ushort)(u >> 16);
}
__device__ __forceinline__ float bf16_to_f(ushort h) {
    unsigned u = (unsigned)h << 16;
    return __builtin_bit_cast(float, u);
}

// Packed-layout element addresses (in elements, not bytes).
// PA (A-operand): [rb=r>>7][kt=k>>5][L][rf=(r>>4)&7][lane=(r&15)+16*((k>>3)&3)][e=k&7]
__device__ __forceinline__ size_t pa_addr(int r, int k, int L) {
    return (size_t)(((r >> 7) * 64 + (k >> 5)) * 3 + L) * 4096
         + (size_t)(((r >> 4) & 7) * 512 + ((r & 15) + 16 * ((k >> 3) & 3)) * 8 + (k & 7));
}
// PB (B-operand): [cb=c>>6][kt=k>>5][L][cf=(c>>4)&3][lane=(c&15)+16*((k>>3)&3)][e=k&7]
__device__ __forceinline__ size_t pb_addr(int c, int k, int L) {
    return (size_t)(((c >> 6) * 64 + (k >> 5)) * 3 + L) * 2048
         + (size_t)(((c >> 4) & 3) * 512 + ((c & 15) + 16 * ((k >> 3) & 3)) * 8 + (k & 7));
}

__device__ __forceinline__ ushort8v mk8(const ushort* p) {
    ushort8v v = {p[0], p[1], p[2], p[3], p[4], p[5], p[6], p[7]};
    return v;
}

__device__ __forceinline__ void gload16(const void* g, void* l) {
    __builtin_amdgcn_global_load_lds(
        (const __attribute__((address_space(1))) unsigned int*)g,
        (__attribute__((address_space(3))) unsigned int*)l, 16, 0, 0);
}

template<int N> __device__ __forceinline__ void vmwait();
template<> __device__ __forceinline__ void vmwait<0>() { asm volatile("s_waitcnt vmcnt(0)" ::: "memory"); }
template<> __device__ __forceinline__ void vmwait<4>() { asm volatile("s_waitcnt vmcnt(4)" ::: "memory"); }
template<> __device__ __forceinline__ void vmwait<5>() { asm volatile("s_waitcnt vmcnt(5)" ::: "memory"); }
__device__ __forceinline__ void lgkm0() { asm volatile("s_waitcnt lgkmcnt(0)" ::: "memory"); }
__device__ __forceinline__ void barfence() {
    __builtin_amdgcn_sched_barrier(0);
    __builtin_amdgcn_s_barrier();
    __builtin_amdgcn_sched_barrier(0);
}

// ---------------- prep: A -> PA-packed of T and PB-packed of T ----------------
// PA(r,k) = T[r][k] = A[k][r];  PB(c,k) = T[k][c] = A[c][k].
__global__ __launch_bounds__(256) void prep_pack(const float* __restrict__ A,
                                                 ushort* PA, ushort* PB) {
    __shared__ float tile[64][65];
    const int tid = threadIdx.x;
    const int bx = blockIdx.x * 64, by = blockIdx.y * 64;
    {
        const int rl = tid >> 2, cq = (tid & 3) * 16;
        const float* src = &A[(size_t)(by + rl) * D + bx + cq];
#pragma unroll
        for (int i = 0; i < 4; ++i) {
            float4 v = *reinterpret_cast<const float4*>(src + i * 4);
            tile[rl][cq + i * 4 + 0] = v.x;
            tile[rl][cq + i * 4 + 1] = v.y;
            tile[rl][cq + i * 4 + 2] = v.z;
            tile[rl][cq + i * 4 + 3] = v.w;
        }
    }
    __syncthreads();
    const int off = tid & 63, kc = tid >> 6;
    ushort hb[16], mb[16], lb[16];
    // PA: r = bx+off, k = by+kc*16+kk, val = A[k][r]
#pragma unroll
    for (int kk = 0; kk < 16; ++kk) {
        const float x = tile[kc * 16 + kk][off];
        const ushort h = bf16_rne(x); const float r1 = x - bf16_to_f(h);
        const ushort md = bf16_rne(r1); const float r2 = r1 - bf16_to_f(md);
        hb[kk] = h; mb[kk] = md; lb[kk] = bf16_rne(r2);
    }
    {
        const int r = bx + off, k0 = by + kc * 16;
#pragma unroll
        for (int g = 0; g < 2; ++g) {
            const size_t a0 = pa_addr(r, k0 + g * 8, 0);
            *(ushort8v*)&PA[a0]        = mk8(hb + g * 8);
            *(ushort8v*)&PA[a0 + 4096] = mk8(mb + g * 8);
            *(ushort8v*)&PA[a0 + 8192] = mk8(lb + g * 8);
        }
    }
    // PB: c = by+off, k = bx+kc*16+kk, val = A[c][k]
#pragma unroll
    for (int kk = 0; kk < 16; ++kk) {
        const float x = tile[off][kc * 16 + kk];
        const ushort h = bf16_rne(x); const float r1 = x - bf16_to_f(h);
        const ushort md = bf16_rne(r1); const float r2 = r1 - bf16_to_f(md);
        hb[kk] = h; mb[kk] = md; lb[kk] = bf16_rne(r2);
    }
    {
        const int cI = by + off, k0 = bx + kc * 16;
#pragma unroll
        for (int g = 0; g < 2; ++g) {
            const size_t b0 = pb_addr(cI, k0 + g * 8, 0);
            *(ushort8v*)&PB[b0]        = mk8(hb + g * 8);
            *(ushort8v*)&PB[b0 + 2048] = mk8(mb + g * 8);
            *(ushort8v*)&PB[b0 + 4096] = mk8(lb + g * 8);
        }
    }
}

// ---------------- split y row 0 into PA-packed (row 0 of an rb=0 block) ----------------
__global__ void split_y(const float* __restrict__ y, ushort* YP) {
    const int k = blockIdx.x * 256 + threadIdx.x;
    if (k < D) {
        const float x = y[k];
        const ushort h = bf16_rne(x); const float r1 = x - bf16_to_f(h);
        const ushort md = bf16_rne(r1); const float r2 = r1 - bf16_to_f(md);
        YP[pa_addr(0, k, 0)] = h;
        YP[pa_addr(0, k, 1)] = md;
        YP[pa_addr(0, k, 2)] = bf16_rne(r2);
    }
}

// ---------------- split-bf16 MFMA GEMM: C[M][2048] = X * W ----------------
// X: PA-packed (rows m0..m0+127 via rb = m0>>7). W: PB-packed.
// Tile 128x64, 8 waves 4Mx2N, wave tile 32x32, BK=32, 64 k-steps.
// LDS per buffer: A 24KB ([L][rf] frags) + B 12KB ([L][cf] frags) = 36KB, x2.
template<bool WF32, bool WNORM, bool WTRANS>
__global__ __launch_bounds__(512, 4)
void gemm3(const ushort* X, const ushort* W, float* Cf,
           ushort* PAo, ushort* PBo, int M, int ro) {
    __shared__ __align__(16) char smem[2 * 36864];
    char* ldsc = (char*)smem;
    const int tid = threadIdx.x;
    const int w = tid >> 6, lane = tid & 63;

    // XCD-aware bijective swizzle (all grids have nwg % 8 == 0)
    const int gx = gridDim.x;
    const int nwg = gx * gridDim.y;
    int id = blockIdx.y * gx + blockIdx.x;
    { const int cpx = nwg >> 3; id = (id & 7) * cpx + (id >> 3); }
    const int n0 = (id % gx) * 64;
    const int m0 = (id / gx) * 128;

    const int wm = w >> 1, wn = w & 1;
    const int wr = wm * 32, wc = wn * 32;

    // staging bases: per (rb,kt) A-block = 24576 B, B-block = 12288 B, both linear
    const char* gA = (const char*)X + (size_t)(m0 >> 7) * 64 * 24576 + (size_t)tid * 16;
    const char* gB = (const char*)W + (size_t)(n0 >> 6) * 64 * 12288 + (size_t)tid * 16;
    const int luA = w * 1024;

    auto stage = [&](int off, int kt) {
        const char* a = gA + (size_t)kt * 24576;
        const char* b = gB + (size_t)kt * 12288;
#pragma unroll
        for (int s = 0; s < 3; ++s)
            gload16(a + s * 8192, ldsc + off + s * 8192 + luA);
        gload16(b, ldsc + off + 24576 + luA);
        if (w < 4) gload16(b + 8192, ldsc + off + 24576 + 8192 + luA);
    };

    // fragment ds_read byte offsets: frag_base + lane*16 (conflict-free)
    int aoff[3][2], boff[3][2];
#pragma unroll
    for (int L = 0; L < 3; ++L) {
#pragma unroll
        for (int q = 0; q < 2; ++q)
            aoff[L][q] = (L * 8 + wm * 2 + q) * 1024 + lane * 16;
#pragma unroll
        for (int nr = 0; nr < 2; ++nr)
            boff[L][nr] = 24576 + (L * 4 + wn * 2 + nr) * 1024 + lane * 16;
    }

    f32x4 acc[2][2] = {};

    auto compute = [&](int off) {
        short8 af[3][2], bf[3][2];
#pragma unroll
        for (int L = 0; L < 3; ++L) {
#pragma unroll
            for (int q = 0; q < 2; ++q)
                af[L][q] = *(const short8*)(ldsc + off + aoff[L][q]);
#pragma unroll
            for (int nr = 0; nr < 2; ++nr)
                bf[L][nr] = *(const short8*)(ldsc + off + boff[L][nr]);
        }
        __builtin_amdgcn_s_setprio(1);
#define PROD(La, Lb) \
        acc[0][0] = __builtin_amdgcn_mfma_f32_16x16x32_bf16(af[La][0], bf[Lb][0], acc[0][0], 0, 0, 0); \
        acc[0][1] = __builtin_amdgcn_mfma_f32_16x16x32_bf16(af[La][0], bf[Lb][1], acc[0][1], 0, 0, 0); \
        acc[1][0] = __builtin_amdgcn_mfma_f32_16x16x32_bf16(af[La][1], bf[Lb][0], acc[1][0], 0, 0, 0); \
        acc[1][1] = __builtin_amdgcn_mfma_f32_16x16x32_bf16(af[La][1], bf[Lb][1], acc[1][1], 0, 0, 0);
        PROD(2, 0) PROD(1, 1) PROD(0, 2) PROD(1, 0) PROD(0, 1) PROD(0, 0)
#undef PROD
        __builtin_amdgcn_s_setprio(0);
    };

    // pipelined K-loop: 64 steps, 2-buffer ring, counted vmcnt (never 0 in loop)
    stage(0, 0);
    for (int t = 0; t < 63; ++t) {
        stage(((t + 1) & 1) * 36864, t + 1);
        if (w < 4) vmwait<5>(); else vmwait<4>();
        barfence();
        compute((t & 1) * 36864);
        lgkm0();
        barfence();
    }
    vmwait<0>();
    barfence();
    compute(36864);

    // epilogue: C/D layout col = lane&15, row = (lane>>4)*4 + j (verified)
    const int row0 = m0 + wr + (lane >> 4) * 4;
    const int col0 = n0 + wc + (lane & 15);
#pragma unroll
    for (int mr = 0; mr < 2; ++mr) {
#pragma unroll
        for (int nr = 0; nr < 2; ++nr) {
            const int c = col0 + nr * 16;
            const int rb0 = row0 + mr * 16;
            ushort hs[4], ms[4], ls[4];
#pragma unroll
            for (int j = 0; j < 4; ++j) {
                const float v = acc[mr][nr][j];
                const ushort h = bf16_rne(v);
                const float r1 = v - bf16_to_f(h);
                const ushort md = bf16_rne(r1);
                const float r2 = r1 - bf16_to_f(md);
                const ushort lo = bf16_rne(r2);
                hs[j] = h; ms[j] = md; ls[j] = lo;
                const int r = rb0 + j;
                if constexpr (WF32) {
                    if (r < M) Cf[(size_t)r * D + c] = v;
                }
                if constexpr (WNORM) {
                    if (r < M) {
                        const int ra = r + ro;
                        const size_t a0 = pa_addr(ra, c, 0);
                        PAo[a0] = h; PAo[a0 + 4096] = md; PAo[a0 + 8192] = lo;
                    }
                }
            }
            if constexpr (WTRANS) {
                if (rb0 + 3 < M) {
                    const size_t b0 = pb_addr(c, rb0, 0);
                    ushort4v hv = {hs[0], hs[1], hs[2], hs[3]};
                    ushort4v mv = {ms[0], ms[1], ms[2], ms[3]};
                    ushort4v lv = {ls[0], ls[1], ls[2], ls[3]};
                    *(ushort4v*)&PBo[b0]        = hv;
                    *(ushort4v*)&PBo[b0 + 2048] = mv;
                    *(ushort4v*)&PBo[b0 + 4096] = lv;
                }
            }
        }
    }
}

// ================= fp32 fallback (round-1, known-good) =================
__global__ void transpose_k(const float* __restrict__ A, float* __restrict__ T) {
    __shared__ float tile[32][33];
    const int bx = blockIdx.x * 32, by = blockIdx.y * 32;
    const int tx = threadIdx.x, ty = threadIdx.y;
#pragma unroll
    for (int i = 0; i < 32; i += 8)
        tile[ty + i][tx] = A[(size_t)(by + ty + i) * D + bx + tx];
    __syncthreads();
#pragma unroll
    for (int i = 0; i < 32; i += 8)
        T[(size_t)(bx + ty + i) * D + by + tx] = tile[tx][ty + i];
}

__global__ __launch_bounds__(256) void gemm_rows(const float* __restrict__ X,
                                                 const float* __restrict__ W,
                                                 float* __restrict__ C, int M) {
    __shared__ float As[16][34];
    __shared__ float Bs[16][68];
    const int n0 = blockIdx.x * 64;
    const int m0 = blockIdx.y * 32;
    const int tid = threadIdx.x;
    const int ty = tid >> 4, tx = tid & 15;
    const int rs = tid >> 3;
    const int ks = (tid & 7) * 2;
    const int rclamp = min(m0 + rs, M - 1);
    const int kb = tid >> 4;
    const int nb = (tid & 15) * 4;
    float acc[2][4] = {{0.f, 0.f, 0.f, 0.f}, {0.f, 0.f, 0.f, 0.f}};
    for (int k0 = 0; k0 < D; k0 += 16) {
        float2 xa = *reinterpret_cast<const float2*>(&X[(size_t)rclamp * D + k0 + ks]);
        float4 wb = *reinterpret_cast<const float4*>(&W[(size_t)(k0 + kb) * D + n0 + nb]);
        As[ks][rs] = xa.x;
        As[ks + 1][rs] = xa.y;
        *reinterpret_cast<float4*>(&Bs[kb][nb]) = wb;
        __syncthreads();
#pragma unroll
        for (int kk = 0; kk < 16; ++kk) {
            float2 a = *reinterpret_cast<const float2*>(&As[kk][ty * 2]);
            float4 b = *reinterpret_cast<const float4*>(&Bs[kk][tx * 4]);
            acc[0][0] += a.x * b.x; acc[0][1] += a.x * b.y;
            acc[0][2] += a.x * b.z; acc[0][3] += a.x * b.w;
            acc[1][0] += a.y * b.x; acc[1][1] += a.y * b.y;
            acc[1][2] += a.y * b.z; acc[1][3] += a.y * b.w;
        }
        __syncthreads();
    }
#pragma unroll
    for (int i = 0; i < 2; ++i) {
        const int m = m0 + ty * 2 + i;
        if (m < M) {
            float4 v = make_float4(acc[i][0], acc[i][1], acc[i][2], acc[i][3]);
            *reinterpret_cast<float4*>(&C[(size_t)m * D + n0 + tx * 4]) = v;
        }
    }
}

__global__ __launch_bounds__(256, 2) void gemm_big(const float* __restrict__ X,
                                                   const float* __restrict__ W,
                                                   float* __restrict__ C) {
    __shared__ float As[16][132];
    __shared__ float Bs[16][68];
    const int n0 = blockIdx.x * 64;
    const int m0 = blockIdx.y * 128;
    const int tid = threadIdx.x;
    const int ty = tid >> 4, tx = tid & 15;
    const int ra = tid >> 2;
    const int ka = (tid & 3) * 4;
    const int kb = tid >> 4;
    const int nb = (tid & 15) * 4;
    float acc[8][4];
#pragma unroll
    for (int i = 0; i < 8; ++i) { acc[i][0] = 0.f; acc[i][1] = 0.f; acc[i][2] = 0.f; acc[i][3] = 0.f; }
    for (int k0 = 0; k0 < D; k0 += 16) {
        float4 a0 = *reinterpret_cast<const float4*>(&X[(size_t)(m0 + ra) * D + k0 + ka]);
        float4 a1 = *reinterpret_cast<const float4*>(&X[(size_t)(m0 + ra + 64) * D + k0 + ka]);
        float4 wb = *reinterpret_cast<const float4*>(&W[(size_t)(k0 + kb) * D + n0 + nb]);
        As[ka][ra] = a0.x; As[ka + 1][ra] = a0.y; As[ka + 2][ra] = a0.z; As[ka + 3][ra] = a0.w;
        As[ka][ra + 64] = a1.x; As[ka + 1][ra + 64] = a1.y;
        As[ka + 2][ra + 64] = a1.z; As[ka + 3][ra + 64] = a1.w;
        *reinterpret_cast<float4*>(&Bs[kb][nb]) = wb;
        __syncthreads();
#pragma unroll
        for (int kk = 0; kk < 16; ++kk) {
            float4 a04 = *reinterpret_cast<const float4*>(&As[kk][ty * 8]);
            float4 a14 = *reinterpret_cast<const float4*>(&As[kk][ty * 8 + 4]);
            float4 b4  = *reinterpret_cast<const float4*>(&Bs[kk][tx * 4]);
            const float av[8] = {a04.x, a04.y, a04.z, a04.w, a14.x, a14.y, a14.z, a14.w};
            const float bv[4] = {b4.x, b4.y, b4.z, b4.w};
#pragma unroll
            for (int i = 0; i < 8; ++i)
#pragma unroll
                for (int j = 0; j < 4; ++j)
                    acc[i][j] += av[i] * bv[j];
        }
        __syncthreads();
    }
#pragma unroll
    for (int i = 0; i < 8; ++i) {
        float4 v = make_float4(acc[i][0], acc[i][1], acc[i][2], acc[i][3]);
        *reinterpret_cast<float4*>(&C[(size_t)(m0 + ty * 8 + i) * D + n0 + tx * 4]) = v;
    }
}

__global__ void matvec_rowdot(const float* __restrict__ A, const float* __restrict__ y,
                              float* __restrict__ out) {
    const int wave = threadIdx.x >> 6, lane = threadIdx.x & 63;
    const int row = blockIdx.x * 4 + wave;
    const float* ar = A + (size_t)row * D;
    float s = 0.f;
#pragma unroll 8
    for (int k = lane; k < D; k += 64) s += ar[k] * y[k];
#pragma unroll
    for (int off = 32; off; off >>= 1) s += __shfl_down(s, off);
    if (lane == 0) out[row] = s;
}

// ================= host =================
extern "C" void kernel_launch(void* const* d_in, const int* in_sizes, int n_in,
                              void* d_out, int out_size, void* d_ws, size_t ws_size,
                              hipStream_t stream) {
    const float* A = (const float*)d_in[0];
    const float* y_init = (const float*)d_in[1];
    float* out = (float*)d_out;

    const size_t paFull = (size_t)16 * 64 * 24576;  // 24 MB (PA of 2048 rows)
    const size_t pbFull = (size_t)32 * 64 * 12288;  // 24 MB (PB of 2048 cols)
    const size_t paRing = (size_t)8 * 64 * 24576;   // 12 MB (PA of 1024 rows)
    const size_t need = 2 * paFull + 2 * pbFull + 2 * paRing;  // 120 MB

    if (ws_size >= need) {
        char* c = (char*)d_ws;
        ushort *PT[2], *PN[2], *rg[2];
        PT[0] = (ushort*)c; c += pbFull;
        PT[1] = (ushort*)c; c += pbFull;
        PN[0] = (ushort*)c; c += paFull;
        PN[1] = (ushort*)c; c += paFull;
        rg[0] = (ushort*)c; c += paRing;
        rg[1] = (ushort*)c; c += paRing;
        ushort* YP = rg[1];  // seed block aliases ring[1] (first written at chain j=1)

        prep_pack<<<dim3(32, 32), 256, 0, stream>>>(A, PN[0], PT[0]);
        split_y<<<8, 256, 0, stream>>>(y_init, YP);

        // seed: rows[0] = y1 * T
        gemm3<true, true, false><<<dim3(32, 1), 512, 0, stream>>>(
            YP, PT[0], out, rg[0], nullptr, 1, 0);

        int cur = 0;
        for (int i = 0; i < 10; ++i) {
            const int m = 1 << i;
            // doubling: rows[m..2m) = rows[0..m) * T^m
            gemm3<true, true, false><<<dim3(32, (m + 127) / 128), 512, 0, stream>>>(
                rg[0], PT[cur], out + (size_t)m * D, rg[0], nullptr, m, m);
            // squaring: T^m -> T^2m
            if (i < 9)
                gemm3<false, true, true><<<dim3(32, 16), 512, 0, stream>>>(
                    PN[cur], PT[cur], nullptr, PN[cur ^ 1], PT[cur ^ 1], 2048, 0);
            else
                gemm3<false, false, true><<<dim3(32, 16), 512, 0, stream>>>(
                    PN[cur], PT[cur], nullptr, nullptr, PT[cur ^ 1], 2048, 0);
            cur ^= 1;
        }

        // chain: rows[j*KB..(j+1)*KB) = rows[(j-1)*KB..) * T^KB
        for (int j = 1; j < STEPS / KB; ++j) {
            if (j < STEPS / KB - 1)
                gemm3<true, true, false><<<dim3(32, 8), 512, 0, stream>>>(
                    rg[(j - 1) & 1], PT[cur], out + (size_t)j * KB * D, rg[j & 1],
                    nullptr, KB, 0);
            else
                gemm3<true, false, false><<<dim3(32, 8), 512, 0, stream>>>(
                    rg[(j - 1) & 1], PT[cur], out + (size_t)j * KB * D, nullptr,
                    nullptr, KB, 0);
        }
    } else if (ws_size >= 2 * (size_t)D * D * sizeof(float)) {
        // fp32 fallback (round-1 path, known-good)
        float* Pa = (float*)d_ws;
        float* Pb = Pa + (size_t)D * D;
        transpose_k<<<dim3(D / 32, D / 32), dim3(32, 8), 0, stream>>>(A, Pa);
        gemm_rows<<<dim3(D / 64, 1), 256, 0, stream>>>(y_init, Pa, out, 1);
        float* cur = Pa;
        float* nxt = Pb;
        for (int m = 1; m < 256; m <<= 1) {
            gemm_rows<<<dim3(D / 64, (m + 31) / 32), 256, 0, stream>>>(
                out, cur, out + (size_t)m * D, m);
            gemm_big<<<dim3(D / 64, D / 128), 256, 0, stream>>>(cur, cur, nxt);
            float* t = cur; cur = nxt; nxt = t;
        }
        for (int j = 1; j < STEPS / 256; ++j) {
            gemm_rows<<<dim3(D / 64, 256 / 32), 256, 0, stream>>>(
                out + (size_t)(j - 1) * 256 * D, cur, out + (size_t)j * 256 * D, 256);
        }
    } else {
        matvec_rowdot<<<D / 4, 256, 0, stream>>>(A, y_init, out);
        for (int t = 1; t < STEPS; ++t)
            matvec_rowdot<<<D / 4, 256, 0, stream>>>(A, out + (size_t)(t - 1) * D,
                                                     out + (size_t)t * D);
    }
}

// Round 5
// 1680.465 us; speedup vs baseline: 3.1983x; 1.0625x over previous
//
#include <hip/hip_runtime.h>

// LinearRNN: ys[t] = A^(t+1) @ y_init[0], t = 0..8191, D = 2048.
// Row-vector convention: T = A^T, rows[t] = y1 * T^(t+1).
// fp32 -> 3 bf16 limbs (h,m,l); 6 limb-product MFMAs (16x16x32) ~= fp32 GEMM.
// Fragment-packed operands in global memory (1KB per 16x32 fragment); staging is
// linear global_load_lds; ds_read_b128 = frag_base + lane*16 (0 bank conflicts).
// R5: wave tile 64x32 (18 ds_read per 48 MFMA -> LDS no longer binding);
// KB=2048 (11 squarings + 3 chain GEMMs, all 512-WG / 2 blocks/CU);
// doubling fused into the squaring launch (shared B operand, extra grid-y rows).

#define D 2048
#define STEPS 8192
#define KB2 2048

typedef __attribute__((ext_vector_type(8))) short short8;
typedef __attribute__((ext_vector_type(4))) float f32x4;
typedef __attribute__((ext_vector_type(4))) unsigned short ushort4v;
typedef __attribute__((ext_vector_type(8))) unsigned short ushort8v;
typedef unsigned short ushort;

__device__ __forceinline__ ushort bf16_rne(float v) {
    unsigned u = __builtin_bit_cast(unsigned, v);
    u += 0x7fffu + ((u >> 16) & 1u);
    return (ushort)(u >> 16);
}
__device__ __forceinline__ float bf16_to_f(ushort h) {
    unsigned u = (unsigned)h << 16;
    return __builtin_bit_cast(float, u);
}

// Packed-layout element addresses (in elements).
// PA (A-operand): [rb=r>>7][kt=k>>5][L][rf=(r>>4)&7][lane=(r&15)+16*((k>>3)&3)][e=k&7]
__device__ __forceinline__ size_t pa_addr(int r, int k, int L) {
    return (size_t)(((r >> 7) * 64 + (k >> 5)) * 3 + L) * 4096
         + (size_t)(((r >> 4) & 7) * 512 + ((r & 15) + 16 * ((k >> 3) & 3)) * 8 + (k & 7));
}
// PB (B-operand): [cb=c>>6][kt=k>>5][L][cf=(c>>4)&3][lane=(c&15)+16*((k>>3)&3)][e=k&7]
__device__ __forceinline__ size_t pb_addr(int c, int k, int L) {
    return (size_t)(((c >> 6) * 64 + (k >> 5)) * 3 + L) * 2048
         + (size_t)(((c >> 4) & 3) * 512 + ((c & 15) + 16 * ((k >> 3) & 3)) * 8 + (k & 7));
}

__device__ __forceinline__ ushort8v mk8(const ushort* p) {
    ushort8v v = {p[0], p[1], p[2], p[3], p[4], p[5], p[6], p[7]};
    return v;
}

__device__ __forceinline__ void gload16(const void* g, void* l) {
    __builtin_amdgcn_global_load_lds(
        (const __attribute__((address_space(1))) unsigned int*)g,
        (__attribute__((address_space(3))) unsigned int*)l, 16, 0, 0);
}

template<int N> __device__ __forceinline__ void vmwait();
template<> __device__ __forceinline__ void vmwait<0>() { asm volatile("s_waitcnt vmcnt(0)" ::: "memory"); }
template<> __device__ __forceinline__ void vmwait<9>() { asm volatile("s_waitcnt vmcnt(9)" ::: "memory"); }
__device__ __forceinline__ void lgkm0() { asm volatile("s_waitcnt lgkmcnt(0)" ::: "memory"); }
__device__ __forceinline__ void barfence() {
    __builtin_amdgcn_sched_barrier(0);
    __builtin_amdgcn_s_barrier();
    __builtin_amdgcn_sched_barrier(0);
}

// ---------------- prep: A -> PA-packed of T and PB-packed of T ----------------
// PA(r,k) = T[r][k] = A[k][r];  PB(c,k) = T[k][c] = A[c][k].
__global__ __launch_bounds__(256) void prep_pack(const float* __restrict__ A,
                                                 ushort* PA, ushort* PB) {
    __shared__ float tile[64][65];
    const int tid = threadIdx.x;
    const int bx = blockIdx.x * 64, by = blockIdx.y * 64;
    {
        const int rl = tid >> 2, cq = (tid & 3) * 16;
        const float* src = &A[(size_t)(by + rl) * D + bx + cq];
#pragma unroll
        for (int i = 0; i < 4; ++i) {
            float4 v = *reinterpret_cast<const float4*>(src + i * 4);
            tile[rl][cq + i * 4 + 0] = v.x;
            tile[rl][cq + i * 4 + 1] = v.y;
            tile[rl][cq + i * 4 + 2] = v.z;
            tile[rl][cq + i * 4 + 3] = v.w;
        }
    }
    __syncthreads();
    const int off = tid & 63, kc = tid >> 6;
    ushort hb[16], mb[16], lb[16];
    // PA: r = bx+off, k = by+kc*16+kk, val = A[k][r]
#pragma unroll
    for (int kk = 0; kk < 16; ++kk) {
        const float x = tile[kc * 16 + kk][off];
        const ushort h = bf16_rne(x); const float r1 = x - bf16_to_f(h);
        const ushort md = bf16_rne(r1); const float r2 = r1 - bf16_to_f(md);
        hb[kk] = h; mb[kk] = md; lb[kk] = bf16_rne(r2);
    }
    {
        const int r = bx + off, k0 = by + kc * 16;
#pragma unroll
        for (int g = 0; g < 2; ++g) {
            const size_t a0 = pa_addr(r, k0 + g * 8, 0);
            *(ushort8v*)&PA[a0]        = mk8(hb + g * 8);
            *(ushort8v*)&PA[a0 + 4096] = mk8(mb + g * 8);
            *(ushort8v*)&PA[a0 + 8192] = mk8(lb + g * 8);
        }
    }
    // PB: c = by+off, k = bx+kc*16+kk, val = A[c][k]
#pragma unroll
    for (int kk = 0; kk < 16; ++kk) {
        const float x = tile[off][kc * 16 + kk];
        const ushort h = bf16_rne(x); const float r1 = x - bf16_to_f(h);
        const ushort md = bf16_rne(r1); const float r2 = r1 - bf16_to_f(md);
        hb[kk] = h; mb[kk] = md; lb[kk] = bf16_rne(r2);
    }
    {
        const int cI = by + off, k0 = bx + kc * 16;
#pragma unroll
        for (int g = 0; g < 2; ++g) {
            const size_t b0 = pb_addr(cI, k0 + g * 8, 0);
            *(ushort8v*)&PB[b0]        = mk8(hb + g * 8);
            *(ushort8v*)&PB[b0 + 2048] = mk8(mb + g * 8);
            *(ushort8v*)&PB[b0 + 4096] = mk8(lb + g * 8);
        }
    }
}

// ---------------- split y row 0, replicated into all 128 rows of rb=0 block ----------------
// (lets the seed GEMM stage the block without row clamping)
__global__ void split_y(const float* __restrict__ y, ushort* YP) {
    const int t = blockIdx.x * 256 + threadIdx.x;  // 128 blocks x 256 = 32768
    const int r = t >> 8;        // 0..127
    const int k0 = (t & 255) * 8;
    ushort h[8], m[8], l[8];
#pragma unroll
    for (int e = 0; e < 8; ++e) {
        const float x = y[k0 + e];
        const ushort hh = bf16_rne(x); const float r1 = x - bf16_to_f(hh);
        const ushort mm = bf16_rne(r1); const float r2 = r1 - bf16_to_f(mm);
        h[e] = hh; m[e] = mm; l[e] = bf16_rne(r2);
    }
    const size_t a0 = pa_addr(r, k0, 0);
    *(ushort8v*)&YP[a0]        = mk8(h);
    *(ushort8v*)&YP[a0 + 4096] = mk8(m);
    *(ushort8v*)&YP[a0 + 8192] = mk8(l);
}

// ---------------- split-bf16 MFMA GEMM (+ optional fused doubling rows) ----------------
// Block 128x64, 256 thr, 4 waves 2Mx2N, wave tile 64x32, BK=32, 64 k-steps.
// blockIdx.y < 16: "squaring" rows, A = Xsq (M=2048), outputs PBo (+PNo if wantPN)
//   unless PBo==nullptr, in which case chain-type outputs (outF/PAout, mask r<M).
// blockIdx.y >= 16 (fused grids only): doubling rows, A = Xdbl rows m0.., chain-type
//   outputs with mask r<M and row offset ro.
__global__ __launch_bounds__(256, 2)
void gemm3(const ushort* __restrict__ Xsq, const ushort* __restrict__ Xdbl,
           const ushort* __restrict__ W,
           float* __restrict__ outF, ushort* __restrict__ PAout, int ro,
           ushort* __restrict__ PNo, ushort* __restrict__ PBo,
           int M, int wantPN) {
    __shared__ __align__(16) char smem[2 * 36864];
    char* ldsc = (char*)smem;
    const int tid = threadIdx.x;
    const int w = tid >> 6, lane = tid & 63;

    const bool dbl = (blockIdx.y >= 16);
    int n0, m0;
    if (!dbl) {
        const int gy = (int)gridDim.y;
        const int nwg = 32 * (gy < 16 ? gy : 16);
        int id = blockIdx.y * 32 + blockIdx.x;
        const int cpx = nwg >> 3; id = (id & 7) * cpx + (id >> 3);
        n0 = (id & 31) * 64;
        m0 = (id >> 5) * 128;
    } else {
        const int nwg = 32 * ((int)gridDim.y - 16);
        int id = (blockIdx.y - 16) * 32 + blockIdx.x;
        const int cpx = nwg >> 3; id = (id & 7) * cpx + (id >> 3);
        n0 = (id & 31) * 64;
        m0 = (id / 32) * 128;
    }
    const ushort* X = dbl ? Xdbl : Xsq;
    const bool sq = (!dbl) && (PBo != nullptr);

    const int wm = w >> 1, wn = w & 1;

    // staging: per (rb,kt) A-block = 24576 B, B-block = 12288 B, both linear
    const char* gA = (const char*)X + (size_t)(m0 >> 7) * 64 * 24576 + (size_t)tid * 16;
    const char* gB = (const char*)W + (size_t)(n0 >> 6) * 64 * 12288 + (size_t)tid * 16;

    auto stage = [&](int off, int kt) {
        const char* a = gA + (size_t)kt * 24576;
        const char* b = gB + (size_t)kt * 12288;
#pragma unroll
        for (int s = 0; s < 6; ++s)
            gload16(a + s * 4096, ldsc + off + s * 4096 + w * 1024);
#pragma unroll
        for (int s = 0; s < 3; ++s)
            gload16(b + s * 4096, ldsc + off + 24576 + s * 4096 + w * 1024);
    };

    // fragment ds_read byte offsets: frag_base + lane*16 (conflict-free)
    int aoff[3][4], boff[3][2];
#pragma unroll
    for (int L = 0; L < 3; ++L) {
#pragma unroll
        for (int q = 0; q < 4; ++q)
            aoff[L][q] = (L * 8 + wm * 4 + q) * 1024 + lane * 16;
#pragma unroll
        for (int nr = 0; nr < 2; ++nr)
            boff[L][nr] = 24576 + (L * 4 + wn * 2 + nr) * 1024 + lane * 16;
    }

    f32x4 acc[4][2] = {};

    auto compute = [&](int off) {
        short8 af[3][4], bf[3][2];
#pragma unroll
        for (int L = 0; L < 3; ++L) {
#pragma unroll
            for (int q = 0; q < 4; ++q)
                af[L][q] = *(const short8*)(ldsc + off + aoff[L][q]);
#pragma unroll
            for (int nr = 0; nr < 2; ++nr)
                bf[L][nr] = *(const short8*)(ldsc + off + boff[L][nr]);
        }
        __builtin_amdgcn_s_setprio(1);
        // product-major, ascending magnitude; 8 independent MFMAs per product
#define PROD(La, Lb) \
        _Pragma("unroll") \
        for (int q = 0; q < 4; ++q) { \
            acc[q][0] = __builtin_amdgcn_mfma_f32_16x16x32_bf16(af[La][q], bf[Lb][0], acc[q][0], 0, 0, 0); \
            acc[q][1] = __builtin_amdgcn_mfma_f32_16x16x32_bf16(af[La][q], bf[Lb][1], acc[q][1], 0, 0, 0); \
        }
        PROD(2, 0) PROD(1, 1) PROD(0, 2) PROD(1, 0) PROD(0, 1) PROD(0, 0)
#undef PROD
        __builtin_amdgcn_s_setprio(0);
    };

    // pipelined K-loop: 64 steps, 2-buffer ring, counted vmcnt (never 0 in loop)
    stage(0, 0);
    for (int t = 0; t < 63; ++t) {
        stage(((t + 1) & 1) * 36864, t + 1);
        vmwait<9>();
        barfence();
        compute((t & 1) * 36864);
        lgkm0();
        barfence();
    }
    vmwait<0>();
    barfence();
    compute(36864);

    // epilogue: C/D layout col = lane&15, row = (lane>>4)*4 + j (verified)
    const int row0 = m0 + wm * 64 + (lane >> 4) * 4;
    const int col0 = n0 + wn * 32 + (lane & 15);
#pragma unroll
    for (int q = 0; q < 4; ++q) {
#pragma unroll
        for (int nr = 0; nr < 2; ++nr) {
            const int c = col0 + nr * 16;
            const int rb0 = row0 + q * 16;
            if (sq) {
                ushort hs[4], ms[4], ls[4];
#pragma unroll
                for (int j = 0; j < 4; ++j) {
                    const float v = acc[q][nr][j];
                    const ushort h = bf16_rne(v);
                    const float r1 = v - bf16_to_f(h);
                    const ushort md = bf16_rne(r1);
                    const float r2 = r1 - bf16_to_f(md);
                    hs[j] = h; ms[j] = md; ls[j] = bf16_rne(r2);
                    if (wantPN) {
                        const size_t a0 = pa_addr(rb0 + j, c, 0);
                        PNo[a0] = h; PNo[a0 + 4096] = md; PNo[a0 + 8192] = ls[j];
                    }
                }
                const size_t b0 = pb_addr(c, rb0, 0);
                ushort4v hv = {hs[0], hs[1], hs[2], hs[3]};
                ushort4v mv = {ms[0], ms[1], ms[2], ms[3]};
                ushort4v lv = {ls[0], ls[1], ls[2], ls[3]};
                *(ushort4v*)&PBo[b0]        = hv;
                *(ushort4v*)&PBo[b0 + 2048] = mv;
                *(ushort4v*)&PBo[b0 + 4096] = lv;
            } else {
#pragma unroll
                for (int j = 0; j < 4; ++j) {
                    const int r = rb0 + j;
                    if (r < M) {
                        const float v = acc[q][nr][j];
                        outF[(size_t)r * D + c] = v;
                        if (PAout) {
                            const ushort h = bf16_rne(v);
                            const float r1 = v - bf16_to_f(h);
                            const ushort md = bf16_rne(r1);
                            const float r2 = r1 - bf16_to_f(md);
                            const size_t a0 = pa_addr(r + ro, c, 0);
                            PAout[a0] = h; PAout[a0 + 4096] = md;
                            PAout[a0 + 8192] = bf16_rne(r2);
                        }
                    }
                }
            }
        }
    }
}

// ================= fp32 fallback (round-1, known-good) =================
__global__ void transpose_k(const float* __restrict__ A, float* __restrict__ T) {
    __shared__ float tile[32][33];
    const int bx = blockIdx.x * 32, by = blockIdx.y * 32;
    const int tx = threadIdx.x, ty = threadIdx.y;
#pragma unroll
    for (int i = 0; i < 32; i += 8)
        tile[ty + i][tx] = A[(size_t)(by + ty + i) * D + bx + tx];
    __syncthreads();
#pragma unroll
    for (int i = 0; i < 32; i += 8)
        T[(size_t)(bx + ty + i) * D + by + tx] = tile[tx][ty + i];
}

__global__ __launch_bounds__(256) void gemm_rows(const float* __restrict__ X,
                                                 const float* __restrict__ W,
                                                 float* __restrict__ C, int M) {
    __shared__ float As[16][34];
    __shared__ float Bs[16][68];
    const int n0 = blockIdx.x * 64;
    const int m0 = blockIdx.y * 32;
    const int tid = threadIdx.x;
    const int ty = tid >> 4, tx = tid & 15;
    const int rs = tid >> 3;
    const int ks = (tid & 7) * 2;
    const int rclamp = min(m0 + rs, M - 1);
    const int kb = tid >> 4;
    const int nb = (tid & 15) * 4;
    float acc[2][4] = {{0.f, 0.f, 0.f, 0.f}, {0.f, 0.f, 0.f, 0.f}};
    for (int k0 = 0; k0 < D; k0 += 16) {
        float2 xa = *reinterpret_cast<const float2*>(&X[(size_t)rclamp * D + k0 + ks]);
        float4 wb = *reinterpret_cast<const float4*>(&W[(size_t)(k0 + kb) * D + n0 + nb]);
        As[ks][rs] = xa.x;
        As[ks + 1][rs] = xa.y;
        *reinterpret_cast<float4*>(&Bs[kb][nb]) = wb;
        __syncthreads();
#pragma unroll
        for (int kk = 0; kk < 16; ++kk) {
            float2 a = *reinterpret_cast<const float2*>(&As[kk][ty * 2]);
            float4 b = *reinterpret_cast<const float4*>(&Bs[kk][tx * 4]);
            acc[0][0] += a.x * b.x; acc[0][1] += a.x * b.y;
            acc[0][2] += a.x * b.z; acc[0][3] += a.x * b.w;
            acc[1][0] += a.y * b.x; acc[1][1] += a.y * b.y;
            acc[1][2] += a.y * b.z; acc[1][3] += a.y * b.w;
        }
        __syncthreads();
    }
#pragma unroll
    for (int i = 0; i < 2; ++i) {
        const int m = m0 + ty * 2 + i;
        if (m < M) {
            float4 v = make_float4(acc[i][0], acc[i][1], acc[i][2], acc[i][3]);
            *reinterpret_cast<float4*>(&C[(size_t)m * D + n0 + tx * 4]) = v;
        }
    }
}

__global__ __launch_bounds__(256, 2) void gemm_big(const float* __restrict__ X,
                                                   const float* __restrict__ W,
                                                   float* __restrict__ C) {
    __shared__ float As[16][132];
    __shared__ float Bs[16][68];
    const int n0 = blockIdx.x * 64;
    const int m0 = blockIdx.y * 128;
    const int tid = threadIdx.x;
    const int ty = tid >> 4, tx = tid & 15;
    const int ra = tid >> 2;
    const int ka = (tid & 3) * 4;
    const int kb = tid >> 4;
    const int nb = (tid & 15) * 4;
    float acc[8][4];
#pragma unroll
    for (int i = 0; i < 8; ++i) { acc[i][0] = 0.f; acc[i][1] = 0.f; acc[i][2] = 0.f; acc[i][3] = 0.f; }
    for (int k0 = 0; k0 < D; k0 += 16) {
        float4 a0 = *reinterpret_cast<const float4*>(&X[(size_t)(m0 + ra) * D + k0 + ka]);
        float4 a1 = *reinterpret_cast<const float4*>(&X[(size_t)(m0 + ra + 64) * D + k0 + ka]);
        float4 wb = *reinterpret_cast<const float4*>(&W[(size_t)(k0 + kb) * D + n0 + nb]);
        As[ka][ra] = a0.x; As[ka + 1][ra] = a0.y; As[ka + 2][ra] = a0.z; As[ka + 3][ra] = a0.w;
        As[ka][ra + 64] = a1.x; As[ka + 1][ra + 64] = a1.y;
        As[ka + 2][ra + 64] = a1.z; As[ka + 3][ra + 64] = a1.w;
        *reinterpret_cast<float4*>(&Bs[kb][nb]) = wb;
        __syncthreads();
#pragma unroll
        for (int kk = 0; kk < 16; ++kk) {
            float4 a04 = *reinterpret_cast<const float4*>(&As[kk][ty * 8]);
            float4 a14 = *reinterpret_cast<const float4*>(&As[kk][ty * 8 + 4]);
            float4 b4  = *reinterpret_cast<const float4*>(&Bs[kk][tx * 4]);
            const float av[8] = {a04.x, a04.y, a04.z, a04.w, a14.x, a14.y, a14.z, a14.w};
            const float bv[4] = {b4.x, b4.y, b4.z, b4.w};
#pragma unroll
            for (int i = 0; i < 8; ++i)
#pragma unroll
                for (int j = 0; j < 4; ++j)
                    acc[i][j] += av[i] * bv[j];
        }
        __syncthreads();
    }
#pragma unroll
    for (int i = 0; i < 8; ++i) {
        float4 v = make_float4(acc[i][0], acc[i][1], acc[i][2], acc[i][3]);
        *reinterpret_cast<float4*>(&C[(size_t)(m0 + ty * 8 + i) * D + n0 + tx * 4]) = v;
    }
}

__global__ void matvec_rowdot(const float* __restrict__ A, const float* __restrict__ y,
                              float* __restrict__ out) {
    const int wave = threadIdx.x >> 6, lane = threadIdx.x & 63;
    const int row = blockIdx.x * 4 + wave;
    const float* ar = A + (size_t)row * D;
    float s = 0.f;
#pragma unroll 8
    for (int k = lane; k < D; k += 64) s += ar[k] * y[k];
#pragma unroll
    for (int off = 32; off; off >>= 1) s += __shfl_down(s, off);
    if (lane == 0) out[row] = s;
}

// ================= host =================
extern "C" void kernel_launch(void* const* d_in, const int* in_sizes, int n_in,
                              void* d_out, int out_size, void* d_ws, size_t ws_size,
                              hipStream_t stream) {
    const float* A = (const float*)d_in[0];
    const float* y_init = (const float*)d_in[1];
    float* out = (float*)d_out;

    const size_t packFull = (size_t)16 * 64 * 24576;   // 24 MiB (PA or PB of 2048)
    const size_t need = 5 * packFull;                  // 120 MiB (same as R4)

    if (ws_size >= need) {
        char* c = (char*)d_ws;
        ushort* PT[2]; ushort* PN[2]; ushort* rg[2];
        PT[0] = (ushort*)c; c += packFull;
        PT[1] = (ushort*)c; c += packFull;
        PN[0] = (ushort*)c; c += packFull;
        PN[1] = (ushort*)c; c += packFull;
        rg[0] = (ushort*)c; c += packFull;
        rg[1] = PN[0];        // dead after last squaring read; ring slot 1
        ushort* YP = PN[1];   // seed block read before squaring i=0 writes PN[1]

        prep_pack<<<dim3(32, 32), 256, 0, stream>>>(A, PN[0], PT[0]);
        split_y<<<128, 256, 0, stream>>>(y_init, YP);

        // seed: rows[0] = y1 * T  (chain-type, M=1)
        gemm3<<<dim3(32, 1), 256, 0, stream>>>(
            YP, nullptr, PT[0], out, rg[0], 0, nullptr, nullptr, 1, 0);

        // fused squaring + doubling: i = 0..10
        int cur = 0;
        for (int i = 0; i < 11; ++i) {
            const int m = 1 << i;
            const int nd = (m + 127) / 128;
            gemm3<<<dim3(32, 16 + nd), 256, 0, stream>>>(
                PN[cur], rg[0], PT[cur],
                out + (size_t)m * D, rg[0], m,
                PN[cur ^ 1], PT[cur ^ 1],
                m, (i < 10) ? 1 : 0);
            cur ^= 1;
        }
        // cur == 1: PT[1] = T^2048

        // chain: rows[j*2048..(j+1)*2048) = rows[(j-1)*2048..) * T^2048
        for (int j = 1; j < STEPS / KB2; ++j) {
            gemm3<<<dim3(32, 16), 256, 0, stream>>>(
                rg[(j - 1) & 1], nullptr, PT[cur],
                out + (size_t)j * KB2 * D,
                (j < STEPS / KB2 - 1) ? rg[j & 1] : nullptr, 0,
                nullptr, nullptr, 2048, 0);
        }
    } else if (ws_size >= 2 * (size_t)D * D * sizeof(float)) {
        // fp32 fallback (round-1 path, known-good)
        float* Pa = (float*)d_ws;
        float* Pb = Pa + (size_t)D * D;
        transpose_k<<<dim3(D / 32, D / 32), dim3(32, 8), 0, stream>>>(A, Pa);
        gemm_rows<<<dim3(D / 64, 1), 256, 0, stream>>>(y_init, Pa, out, 1);
        float* cur = Pa;
        float* nxt = Pb;
        for (int m = 1; m < 256; m <<= 1) {
            gemm_rows<<<dim3(D / 64, (m + 31) / 32), 256, 0, stream>>>(
                out, cur, out + (size_t)m * D, m);
            gemm_big<<<dim3(D / 64, D / 128), 256, 0, stream>>>(cur, cur, nxt);
            float* t = cur; cur = nxt; nxt = t;
        }
        for (int j = 1; j < STEPS / 256; ++j) {
            gemm_rows<<<dim3(D / 64, 256 / 32), 256, 0, stream>>>(
                out + (size_t)(j - 1) * 256 * D, cur, out + (size_t)j * 256 * D, 256);
        }
    } else {
        matvec_rowdot<<<D / 4, 256, 0, stream>>>(A, y_init, out);
        for (int t = 1; t < STEPS; ++t)
            matvec_rowdot<<<D / 4, 256, 0, stream>>>(A, out + (size_t)(t - 1) * D,
                                                     out + (size_t)t * D);
    }
}